// Round 17
// baseline (733.004 us; speedup 1.0000x reference)
//
#include <hip/hip_runtime.h>

#define NN    48
#define DD    16
#define HH    256
#define EE    2256
#define BB    32
#define NPRED 8
#define LSTR  56
#define PQS   1040                   // PQ per-node stride (floats), de-pow2

typedef __attribute__((ext_vector_type(4))) float f32x4;
typedef __attribute__((ext_vector_type(8))) short short8;

__device__ __forceinline__ float bf2f(unsigned short h) {
    union { unsigned u; float f; } v; v.u = ((unsigned)h) << 16; return v.f;
}
__device__ __forceinline__ unsigned short f2bf(float x) {
    union { float f; unsigned u; } v; v.f = x;
    unsigned r = v.u + 0x7fffu + ((v.u >> 16) & 1u);
    return (unsigned short)(r >> 16);
}
__device__ __forceinline__ unsigned perm_hi16(unsigned xB, unsigned xA, unsigned sel) {
    unsigned d;
    asm("v_perm_b32 %0, %1, %2, %3" : "=v"(d) : "v"(xB), "v"(xA), "s"(sel));
    return d;
}
struct Split3 { unsigned d0, d1, d2; };
__device__ __forceinline__ Split3 split2(float u0, float u1, unsigned sel)
{
    union F { float f; unsigned u; };
    Split3 o;
    F x0, x1; x0.f = u0; x1.f = u1;
    o.d0 = perm_hi16(x1.u, x0.u, sel);
    F h0a, h0b; h0a.u = x0.u & 0xffff0000u; h0b.u = x1.u & 0xffff0000u;
    F e0a, e0b; e0a.f = u0 - h0a.f; e0b.f = u1 - h0b.f;
    o.d1 = perm_hi16(e0b.u, e0a.u, sel);
    F h1a, h1b; h1a.u = e0a.u & 0xffff0000u; h1b.u = e0b.u & 0xffff0000u;
    F e1a, e1b; e1a.f = e0a.f - h1a.f; e1b.f = e0b.f - h1b.f;
    o.d2 = perm_hi16(e1b.u, e1a.u, sel);
    return o;
}
union PackA { unsigned u[4]; short8 s; };

// ---------------------------------------------------------------------------
// Setup (192 blocks) — unchanged (verified).
// ---------------------------------------------------------------------------
__global__ __launch_bounds__(256) void k_setup(
    const float* __restrict__ time_segs,
    const float* __restrict__ edge_types,
    const float* __restrict__ W1,      // (2,32,256)
    const float* __restrict__ W2,      // (2,256,256)
    const float* __restrict__ b1,      // (2,256)
    float* __restrict__ state,
    float* __restrict__ W1T,           // (2,256,32)
    unsigned short* __restrict__ W2f,  // 393216
    float* __restrict__ PQ,
    int* __restrict__ lists,
    int* __restrict__ counts)
{
    const int tid = blockIdx.x * 256 + threadIdx.x;
    const int NT = 192*256;
    for (int i = tid; i < BB*NN*DD; i += NT)
        state[i] = time_segs[i];
    for (int i = tid; i < 2*HH*32; i += NT) {
        const int t = i >> 13, r = i & 8191, h = r >> 5, f = r & 31;
        W1T[i] = W1[(t*32 + f)*HH + h];
    }
    for (int i = tid; i < 2*8*16*64*8; i += NT) {
        const int j  = i & 7, l = (i >> 3) & 63, nt = (i >> 9) & 15;
        const int kt = (i >> 13) & 7, t = (i >> 16) & 1;
        const int k = kt*32 + ((l >> 4) << 3) + j;
        const int n = nt*16 + (l & 15);
        const float w = W2[((size_t)t*HH + k)*HH + n];
        const unsigned short h0 = f2bf(w);  const float r1 = w  - bf2f(h0);
        const unsigned short h1 = f2bf(r1); const float r2 = r1 - bf2f(h1);
        const unsigned short h2 = f2bf(r2);
        const size_t rest = (size_t)kt*8192 + nt*512 + l*8 + j;
        W2f[(size_t)(t*3+0)*65536 + rest] = h0;
        W2f[(size_t)(t*3+1)*65536 + rest] = h1;
        W2f[(size_t)(t*3+2)*65536 + rest] = h2;
    }
    for (int i = tid; i < BB*NN*1024; i += NT) {
        const int c  = i & 255;
        const int pq = (i >> 8) & 1;
        const int t  = (i >> 9) & 1;
        const int nb = i >> 10;
        float v = pq ? b1[t*HH + c] : 0.f;
        #pragma unroll
        for (int f = 0; f < DD; ++f)
            v = fmaf(time_segs[nb*DD + f], W1[(t*32 + pq*16 + f)*HH + c], v);
        PQ[(size_t)nb*PQS + (i & 1023)] = v;
    }
    if (tid < BB*NN) {
        const int b = tid / NN;
        const int n = tid % NN;
        int* lst = lists + tid * LSTR;
        int c = 0;
        for (int s = 0; s < NN; ++s) {
            if (s == n) continue;
            const int e = s * 47 + (n > s ? n - 1 : n);
            if (edge_types[((size_t)b*EE + e)*3 + 1] > 0.5f) lst[c++] = s;
        }
        const int c1 = c;
        for (int s = 0; s < NN; ++s) {
            if (s == n) continue;
            const int e = s * 47 + (n > s ? n - 1 : n);
            if (edge_types[((size_t)b*EE + e)*3 + 2] > 0.5f) lst[c++] = s;
        }
        counts[tid*2 + 0] = c1;
        counts[tid*2 + 1] = c - c1;
        for (int i = c; i < LSTR; ++i) lst[i] = 0;
    }
}

// MFMA group for n-tile ii using B-buffer Bx over this wave's <=2 tiles
#define MM(ii, Bx)                                                             \
    _Pragma("unroll")                                                          \
    for (int q2 = 0; q2 < 2; ++q2) {                                           \
        if (qb + q2 >= qloS && qb + q2 < qhiS) {                               \
            f32x4 a = acc[q2][ii];                                             \
            a = __builtin_amdgcn_mfma_f32_16x16x32_bf16(A[q2][2].s, Bx[0], a, 0, 0, 0); \
            a = __builtin_amdgcn_mfma_f32_16x16x32_bf16(A[q2][1].s, Bx[1], a, 0, 0, 0); \
            a = __builtin_amdgcn_mfma_f32_16x16x32_bf16(A[q2][0].s, Bx[2], a, 0, 0, 0); \
            a = __builtin_amdgcn_mfma_f32_16x16x32_bf16(A[q2][1].s, Bx[0], a, 0, 0, 0); \
            a = __builtin_amdgcn_mfma_f32_16x16x32_bf16(A[q2][0].s, Bx[1], a, 0, 0, 0); \
            a = __builtin_amdgcn_mfma_f32_16x16x32_bf16(A[q2][0].s, Bx[0], a, 0, 0, 0); \
            acc[q2][ii] = a;                                                   \
        }                                                                      \
    }

#define LOADB(Bx, nti)                                                         \
    _Pragma("unroll")                                                          \
    for (int p = 0; p < 3; ++p)                                                \
        Bx[p] = *(const short8*)(Wb + (size_t)p*65536 + (size_t)(nti)*512);

// ---------------------------------------------------------------------------
// Encoder v9: 1-wave blocks, grid 12288 = (b, pair, tilequarter, ntq).
// Wave owns <=2 m-tiles x 64 cols: acc[2][4]=32 AGPR + ~85 VGPR < 128-reg
// bucket -> 4 waves/SIMD (launch_bounds 64,4). Zero LDS/barriers.
// Empty quarter-blocks still write zero partials (no early exit).
// ---------------------------------------------------------------------------
__global__ __launch_bounds__(64, 4) void k_enc(
    const int*   __restrict__ lists,
    const int*   __restrict__ counts,
    const float* __restrict__ PQ,
    const unsigned short* __restrict__ W2f,
    const float* __restrict__ b2,    // (2,256)
    float* __restrict__ nm)          // 4 x BB*NN*HH partials
{
    const int lb   = (blockIdx.x & 7)*1536 + (blockIdx.x >> 3);  // XCD cluster
    const int b    = lb / 384;           // 4 batches per XCD
    const int rem  = lb % 384;
    const int pair = rem >> 4;
    const int quar = (rem >> 2) & 3;     // tile quarter
    const int ntq  = rem & 3;            // n-tile quad (cols ntq*64..)
    const int n0   = pair * 2;
    const int lane = threadIdx.x;        // 0..63
    const int c8   = (lane >> 4) * 8;
    const unsigned PSEL = 0x07060302u;

    const int c00 = counts[(b*NN + n0    )*2 + 0];
    const int c10 = counts[(b*NN + n0    )*2 + 1];
    const int c01 = counts[(b*NN + n0 + 1)*2 + 0];
    const int c11 = counts[(b*NN + n0 + 1)*2 + 1];
    const int tA  = c00 + c01, tB = c10 + c11;
    const int tAt = (tA + 15) >> 4, tBt = (tB + 15) >> 4;
    const int tiles = tAt + tBt;
    const int qb = quar * 2;
    const int qe = (qb + 2 < tiles) ? qb + 2 : tiles;  // [qb,qe), may be empty

    // per-lane rowinfo: lanes 0..31 cover 2 tiles x 16 rows
    int info;
    {
        const int myq = qb + (lane >> 4);     // 0..3; valid for lane<32
        const int r   = myq*16 + (lane & 15);
        int g = 4, src = 0;
        if ((lane >> 4) < 2 && myq < qe) {
            if (r < tAt*16) {
                if (r < c00)     { src = lists[(b*NN + n0    )*LSTR + r];        g = 0; }
                else if (r < tA) { src = lists[(b*NN + n0 + 1)*LSTR + (r - c00)]; g = 1; }
            } else {
                const int s = r - tAt*16;
                if (s < c10)     { src = lists[(b*NN + n0    )*LSTR + c00 + s];        g = 2; }
                else if (s < tB) { src = lists[(b*NN + n0 + 1)*LSTR + c01 + (s - c10)]; g = 3; }
            }
        }
        info = src | (g << 8);
    }

    int pbase[2], qbase[2];
    #pragma unroll
    for (int q2 = 0; q2 < 2; ++q2) {
        const int inf = __shfl(info, (q2 << 4) | (lane & 15));
        const int s2  = inf & 255;
        const int nd  = (inf >> 8) & 1;
        const int tq  = (qb + q2 >= tAt) ? 1 : 0;
        pbase[q2] = s2*PQS + tq*512;
        qbase[q2] = (n0 + nd)*PQS + tq*512 + 256;
    }

    f32x4 acc[2][4];
    #pragma unroll
    for (int q2 = 0; q2 < 2; ++q2)
        #pragma unroll
        for (int i = 0; i < 4; ++i)
            acc[q2][i] = (f32x4){0.f, 0.f, 0.f, 0.f};

    const float* PQb = PQ + (size_t)b*NN*PQS;

    if (qb < qe) {
        #pragma unroll 1
        for (int kt = 0; kt < 8; ++kt) {
            const int kc = kt*32 + c8;
            // ---- A-build: both tiles, one load volley ----
            PackA A[2][3];
            #pragma unroll
            for (int q2 = 0; q2 < 2; ++q2) {
                if (qb + q2 < qe) {
                    const float* pr = PQb + pbase[q2] + kc;
                    const float* qr = PQb + qbase[q2] + kc;
                    const float4 Pa = *(const float4*)pr, Pb = *(const float4*)(pr+4);
                    const float4 Qa = *(const float4*)qr, Qb = *(const float4*)(qr+4);
                    const float u0 = fmaxf(Pa.x + Qa.x, 0.f);
                    const float u1 = fmaxf(Pa.y + Qa.y, 0.f);
                    const float u2 = fmaxf(Pa.z + Qa.z, 0.f);
                    const float u3 = fmaxf(Pa.w + Qa.w, 0.f);
                    const float u4 = fmaxf(Pb.x + Qb.x, 0.f);
                    const float u5 = fmaxf(Pb.y + Qb.y, 0.f);
                    const float u6 = fmaxf(Pb.z + Qb.z, 0.f);
                    const float u7 = fmaxf(Pb.w + Qb.w, 0.f);
                    const Split3 s0 = split2(u0, u1, PSEL);
                    const Split3 s1 = split2(u2, u3, PSEL);
                    const Split3 s2 = split2(u4, u5, PSEL);
                    const Split3 s3 = split2(u6, u7, PSEL);
                    A[q2][0].u[0]=s0.d0; A[q2][0].u[1]=s1.d0; A[q2][0].u[2]=s2.d0; A[q2][0].u[3]=s3.d0;
                    A[q2][1].u[0]=s0.d1; A[q2][1].u[1]=s1.d1; A[q2][1].u[2]=s2.d1; A[q2][1].u[3]=s3.d1;
                    A[q2][2].u[0]=s0.d2; A[q2][2].u[1]=s1.d2; A[q2][2].u[2]=s2.d2; A[q2][2].u[3]=s3.d2;
                }
            }
            // ---- MFMA: per type-section, 2-deep B pipeline ----
            #pragma unroll
            for (int sec = 0; sec < 2; ++sec) {
                const int qloS = sec ? (tAt > qb ? tAt : qb) : qb;
                const int qhiS = sec ? qe : (tAt < qe ? tAt : qe);
                if (qloS >= qhiS) continue;
                const unsigned short* Wb = W2f + (size_t)sec*3*65536
                    + (size_t)kt*8192 + (size_t)(ntq*4)*512 + (size_t)lane*8;
                short8 B0[3], B1[3];
                LOADB(B0, 0)
                LOADB(B1, 1)
                MM(0, B0)
                LOADB(B0, 2)
                MM(1, B1)
                LOADB(B1, 3)
                MM(2, B0)
                MM(3, B1)
            }
        }
    }

    // ---- readout: relu(acc+b2), node mask, shfl-reduce, store (always) ----
    float b2v[2][4];
    #pragma unroll
    for (int t = 0; t < 2; ++t)
        #pragma unroll
        for (int i = 0; i < 4; ++i)
            b2v[t][i] = b2[t*HH + (ntq*4 + i)*16 + (lane & 15)];

    float p0[4], p1[4];
    #pragma unroll
    for (int i = 0; i < 4; ++i) { p0[i] = 0.f; p1[i] = 0.f; }
    #pragma unroll
    for (int q2 = 0; q2 < 2; ++q2) {
        if (qb + q2 < qe) {
            const bool secB = (qb + q2 >= tAt);
            int gv[4];
            #pragma unroll
            for (int rr = 0; rr < 4; ++rr)
                gv[rr] = __shfl(info, (q2 << 4) | ((lane >> 4)*4 + rr)) >> 8;
            #pragma unroll
            for (int i = 0; i < 4; ++i) {
                const float bias = secB ? b2v[1][i] : b2v[0][i];
                #pragma unroll
                for (int rr = 0; rr < 4; ++rr) {
                    const float v = fmaxf(acc[q2][i][rr] + bias, 0.f);
                    const bool valid = gv[rr] < 4;
                    p0[i] += (valid && !(gv[rr] & 1)) ? v : 0.f;
                    p1[i] += (valid &&  (gv[rr] & 1)) ? v : 0.f;
                }
            }
        }
    }
    float* nmh = nm + (size_t)quar*BB*NN*HH;
    #pragma unroll
    for (int i = 0; i < 4; ++i) {
        float v0 = p0[i], v1 = p1[i];
        v0 += __shfl_xor(v0, 16); v0 += __shfl_xor(v0, 32);
        v1 += __shfl_xor(v1, 16); v1 += __shfl_xor(v1, 32);
        if ((lane >> 4) == 0) {
            nmh[((size_t)(b*NN + n0  ))*HH + (ntq*4 + i)*16 + lane] = v0;
            nmh[((size_t)(b*NN + n0+1))*HH + (ntq*4 + i)*16 + lane] = v1;
        }
    }
}

// ---------------------------------------------------------------------------
// Decoder: 4 rows/block (384 blocks), XCD-clustered, sums 4 nm partials,
// fused next-step PQ production.
// ---------------------------------------------------------------------------
__global__ __launch_bounds__(256, 2) void k_dec(
    float* __restrict__ state,
    const float* __restrict__ nm,    // 4 partial buffers
    const float* __restrict__ W1, const float* __restrict__ b1,   // (272,256)
    const float* __restrict__ W2, const float* __restrict__ b2,   // (256,256)
    const float* __restrict__ W3, const float* __restrict__ b3,   // (256,16)
    const float* __restrict__ eW1T,  // (2,256,32)
    const float* __restrict__ eb1,   // (2,256)
    float* __restrict__ PQ,
    float* __restrict__ out, int step)
{
    const int lb   = (blockIdx.x & 7)*48 + (blockIdx.x >> 3);
    const int b    = lb / 12;
    const int row0 = (lb % 12) * 4;
    const int c    = threadIdx.x;
    const size_t NMSZ = (size_t)BB*NN*HH;

    __shared__ float in_s[4][272];
    __shared__ float d1s[4][HH];
    __shared__ float stn[4][DD];

    for (int i = c; i < 4*272; i += 256) {
        const int m = i / 272, k = i % 272;
        const int r = row0 + m;
        if (k < DD) {
            in_s[m][k] = state[((size_t)b*NN + r)*DD + k];
        } else {
            const size_t idx = ((size_t)b*NN + r)*HH + (k - DD);
            in_s[m][k] = (nm[idx] + nm[NMSZ + idx])
                       + (nm[2*NMSZ + idx] + nm[3*NMSZ + idx]);
        }
    }
    __syncthreads();

    float a0[4];
    {
        const float bb = b1[c];
        #pragma unroll
        for (int m = 0; m < 4; ++m) a0[m] = bb;
        #pragma unroll 2
        for (int k4 = 0; k4 < 68; ++k4) {
            const float* wr = W1 + (k4*4)*HH;
            const float w0=wr[c], w1_=wr[HH+c], w2_=wr[2*HH+c], w3=wr[3*HH+c];
            #pragma unroll
            for (int m = 0; m < 4; ++m) {
                const float4 h = *(const float4*)&in_s[m][k4*4];
                a0[m] = fmaf(h.x,w0, fmaf(h.y,w1_, fmaf(h.z,w2_, fmaf(h.w,w3, a0[m]))));
            }
        }
        #pragma unroll
        for (int m = 0; m < 4; ++m) d1s[m][c] = fmaxf(a0[m], 0.f);
    }
    __syncthreads();
    {
        const float bb = b2[c];
        #pragma unroll
        for (int m = 0; m < 4; ++m) a0[m] = bb;
        #pragma unroll 2
        for (int k4 = 0; k4 < 64; ++k4) {
            const float* wr = W2 + (k4*4)*HH;
            const float w0=wr[c], w1_=wr[HH+c], w2_=wr[2*HH+c], w3=wr[3*HH+c];
            #pragma unroll
            for (int m = 0; m < 4; ++m) {
                const float4 h = *(const float4*)&d1s[m][k4*4];
                a0[m] = fmaf(h.x,w0, fmaf(h.y,w1_, fmaf(h.z,w2_, fmaf(h.w,w3, a0[m]))));
            }
        }
        __syncthreads();
        #pragma unroll
        for (int m = 0; m < 4; ++m) in_s[m][c] = fmaxf(a0[m], 0.f);
    }
    __syncthreads();
    if (c < 64) {
        const int m = c >> 4, cc = c & 15;
        float a = b3[cc];
        #pragma unroll 4
        for (int k4 = 0; k4 < 64; ++k4) {
            const float4 h = *(const float4*)&in_s[m][k4*4];
            a += h.x*W3[(k4*4+0)*16+cc] + h.y*W3[(k4*4+1)*16+cc]
               + h.z*W3[(k4*4+2)*16+cc] + h.w*W3[(k4*4+3)*16+cc];
        }
        const int r = row0 + m;
        const float v = state[((size_t)b*NN + r)*DD + cc] + a;
        state[((size_t)b*NN + r)*DD + cc] = v;
        out[(((size_t)b*NPRED + step)*NN + r)*DD + cc] = v;
        stn[m][cc] = v;
    }
    __syncthreads();
    float4 sm[4][4];
    #pragma unroll
    for (int m = 0; m < 4; ++m)
        #pragma unroll
        for (int f4 = 0; f4 < 4; ++f4)
            sm[m][f4] = *(const float4*)&stn[m][f4*4];
    #pragma unroll
    for (int k = 0; k < 4; ++k) {
        const int combo = c + 256*k;
        const int cc = combo & 255;
        const int pq = (combo >> 8) & 1;
        const int t  = combo >> 9;
        const float* wc = eW1T + ((size_t)t*HH + cc)*32 + pq*16;
        float4 w[4];
        #pragma unroll
        for (int f4 = 0; f4 < 4; ++f4) w[f4] = ((const float4*)wc)[f4];
        const float bias = pq ? eb1[t*HH + cc] : 0.f;
        #pragma unroll
        for (int m = 0; m < 4; ++m) {
            float v = bias;
            #pragma unroll
            for (int f4 = 0; f4 < 4; ++f4) {
                const float4 s = sm[m][f4];
                v = fmaf(s.x,w[f4].x, fmaf(s.y,w[f4].y, fmaf(s.z,w[f4].z, fmaf(s.w,w[f4].w, v))));
            }
            PQ[(size_t)(b*NN + row0 + m)*PQS + t*512 + pq*256 + cc] = v;
        }
    }
}

// ---------------------------------------------------------------------------
extern "C" void kernel_launch(void* const* d_in, const int* in_sizes, int n_in,
                              void* d_out, int out_size, void* d_ws, size_t ws_size,
                              hipStream_t stream)
{
    const float* time_segs  = (const float*)d_in[0];
    const float* edge_types = (const float*)d_in[1];
    const float* enc_W1 = (const float*)d_in[4];
    const float* enc_b1 = (const float*)d_in[5];
    const float* enc_W2 = (const float*)d_in[6];
    const float* enc_b2 = (const float*)d_in[7];
    const float* dec_W1 = (const float*)d_in[8];
    const float* dec_b1 = (const float*)d_in[9];
    const float* dec_W2 = (const float*)d_in[10];
    const float* dec_b2 = (const float*)d_in[11];
    const float* out_W  = (const float*)d_in[12];
    const float* out_b  = (const float*)d_in[13];
    float* out = (float*)d_out;

    // workspace (~14 MB)
    float* state    = (float*)d_ws;                    // 24576 f
    float* nm       = state + BB*NN*DD;                // 1572864 f (4 partials)
    float* W1T      = nm + 4*BB*NN*HH;                 // 16384 f
    unsigned short* W2f = (unsigned short*)(W1T + 2*HH*32);   // 393216 us
    int*   lists    = (int*)(W2f + 2*3*65536);         // 86016 i
    int*   counts   = lists + BB*NN*LSTR;              // 3072 i
    float* PQ       = (float*)(counts + BB*NN*2);      // 1597440 f

    k_setup<<<192, 256, 0, stream>>>(time_segs, edge_types, enc_W1, enc_W2,
                                     enc_b1, state, W1T, W2f, PQ, lists, counts);
    for (int stp = 0; stp < NPRED; ++stp) {
        k_enc<<<BB*NN*8, 64, 0, stream>>>(lists, counts, PQ, W2f,
                                          enc_b2, nm);
        k_dec<<<BB*12, 256, 0, stream>>>(state, nm,
                                         dec_W1, dec_b1, dec_W2, dec_b2,
                                         out_W, out_b, W1T, enc_b1, PQ, out, stp);
    }
}

// Round 18
// 632.497 us; speedup vs baseline: 1.1589x; 1.1589x over previous
//
#include <hip/hip_runtime.h>

#define NN    48
#define DD    16
#define HH    256
#define EE    2256
#define BB    32
#define NPRED 8
#define LSTR  56
#define PQS   1040                   // PQ per-node stride (floats), de-pow2
#define TMAX  7                      // packed tiles/pair <= 7 (tA+tB<=94)
#define ROWB  80                     // A-plane row stride bytes (5x16B, 2-way banks)
#define APL   (TMAX*16*ROWB)         // 8960 B per plane

typedef __attribute__((ext_vector_type(4))) float f32x4;
typedef __attribute__((ext_vector_type(8))) short short8;

__device__ __forceinline__ float bf2f(unsigned short h) {
    union { unsigned u; float f; } v; v.u = ((unsigned)h) << 16; return v.f;
}
__device__ __forceinline__ unsigned short f2bf(float x) {
    union { float f; unsigned u; } v; v.f = x;
    unsigned r = v.u + 0x7fffu + ((v.u >> 16) & 1u);
    return (unsigned short)(r >> 16);
}
__device__ __forceinline__ unsigned perm_hi16(unsigned xB, unsigned xA, unsigned sel) {
    unsigned d;
    asm("v_perm_b32 %0, %1, %2, %3" : "=v"(d) : "v"(xB), "v"(xA), "s"(sel));
    return d;
}
struct Split3 { unsigned d0, d1, d2; };
__device__ __forceinline__ Split3 split2(float u0, float u1, unsigned sel)
{
    union F { float f; unsigned u; };
    Split3 o;
    F x0, x1; x0.f = u0; x1.f = u1;
    o.d0 = perm_hi16(x1.u, x0.u, sel);
    F h0a, h0b; h0a.u = x0.u & 0xffff0000u; h0b.u = x1.u & 0xffff0000u;
    F e0a, e0b; e0a.f = u0 - h0a.f; e0b.f = u1 - h0b.f;
    o.d1 = perm_hi16(e0b.u, e0a.u, sel);
    F h1a, h1b; h1a.u = e0a.u & 0xffff0000u; h1b.u = e0b.u & 0xffff0000u;
    F e1a, e1b; e1a.f = e0a.f - h1a.f; e1b.f = e0b.f - h1b.f;
    o.d2 = perm_hi16(e1b.u, e1a.u, sel);
    return o;
}
union PackA { unsigned u[4]; short8 s; };

// ---------------------------------------------------------------------------
// Setup (192 blocks) — unchanged (verified).
// ---------------------------------------------------------------------------
__global__ __launch_bounds__(256) void k_setup(
    const float* __restrict__ time_segs,
    const float* __restrict__ edge_types,
    const float* __restrict__ W1,      // (2,32,256)
    const float* __restrict__ W2,      // (2,256,256)
    const float* __restrict__ b1,      // (2,256)
    float* __restrict__ state,
    float* __restrict__ W1T,           // (2,256,32)
    unsigned short* __restrict__ W2f,  // 393216
    float* __restrict__ PQ,
    int* __restrict__ lists,
    int* __restrict__ counts)
{
    const int tid = blockIdx.x * 256 + threadIdx.x;
    const int NT = 192*256;
    for (int i = tid; i < BB*NN*DD; i += NT)
        state[i] = time_segs[i];
    for (int i = tid; i < 2*HH*32; i += NT) {
        const int t = i >> 13, r = i & 8191, h = r >> 5, f = r & 31;
        W1T[i] = W1[(t*32 + f)*HH + h];
    }
    for (int i = tid; i < 2*8*16*64*8; i += NT) {
        const int j  = i & 7, l = (i >> 3) & 63, nt = (i >> 9) & 15;
        const int kt = (i >> 13) & 7, t = (i >> 16) & 1;
        const int k = kt*32 + ((l >> 4) << 3) + j;
        const int n = nt*16 + (l & 15);
        const float w = W2[((size_t)t*HH + k)*HH + n];
        const unsigned short h0 = f2bf(w);  const float r1 = w  - bf2f(h0);
        const unsigned short h1 = f2bf(r1); const float r2 = r1 - bf2f(h1);
        const unsigned short h2 = f2bf(r2);
        const size_t rest = (size_t)kt*8192 + nt*512 + l*8 + j;
        W2f[(size_t)(t*3+0)*65536 + rest] = h0;
        W2f[(size_t)(t*3+1)*65536 + rest] = h1;
        W2f[(size_t)(t*3+2)*65536 + rest] = h2;
    }
    for (int i = tid; i < BB*NN*1024; i += NT) {
        const int c  = i & 255;
        const int pq = (i >> 8) & 1;
        const int t  = (i >> 9) & 1;
        const int nb = i >> 10;
        float v = pq ? b1[t*HH + c] : 0.f;
        #pragma unroll
        for (int f = 0; f < DD; ++f)
            v = fmaf(time_segs[nb*DD + f], W1[(t*32 + pq*16 + f)*HH + c], v);
        PQ[(size_t)nb*PQS + (i & 1023)] = v;
    }
    if (tid < BB*NN) {
        const int b = tid / NN;
        const int n = tid % NN;
        int* lst = lists + tid * LSTR;
        int c = 0;
        for (int s = 0; s < NN; ++s) {
            if (s == n) continue;
            const int e = s * 47 + (n > s ? n - 1 : n);
            if (edge_types[((size_t)b*EE + e)*3 + 1] > 0.5f) lst[c++] = s;
        }
        const int c1 = c;
        for (int s = 0; s < NN; ++s) {
            if (s == n) continue;
            const int e = s * 47 + (n > s ? n - 1 : n);
            if (edge_types[((size_t)b*EE + e)*3 + 2] > 0.5f) lst[c++] = s;
        }
        counts[tid*2 + 0] = c1;
        counts[tid*2 + 1] = c - c1;
        for (int i = c; i < LSTR; ++i) lst[i] = 0;
    }
}

// ---------------------------------------------------------------------------
// Encoder v10: block = (pair, nt-half), 4 waves. A-planes built ONCE per
// block into LDS (448 items / 256 thr), each wave MFMAs all tiles x its
// 2 n-tiles from LDS. A-build redundancy 8x->2x, B traffic 880->560 MB,
// no partial output buffers (block owns 128 complete cols).
// ---------------------------------------------------------------------------
__global__ __launch_bounds__(256, 3) void k_enc(
    const int*   __restrict__ lists,
    const int*   __restrict__ counts,
    const float* __restrict__ PQ,
    const unsigned short* __restrict__ W2f,
    const float* __restrict__ b2,    // (2,256)
    float* __restrict__ node_msg)
{
    const int lb     = (blockIdx.x & 7)*192 + (blockIdx.x >> 3);  // XCD cluster
    const int b      = lb / 48;          // 4 batches per XCD
    const int rem    = lb % 48;
    const int pair   = rem >> 1;
    const int nthalf = rem & 1;
    const int n0     = pair * 2;
    const int tid    = threadIdx.x;
    const int lane   = tid & 63, wave = tid >> 6;
    const unsigned PSEL = 0x07060302u;

    __shared__ __align__(16) char Apl[3*APL];   // 26.9 KB
    __shared__ int rowinfo_s[TMAX*16];

    const int c00 = counts[(b*NN + n0    )*2 + 0];
    const int c10 = counts[(b*NN + n0    )*2 + 1];
    const int c01 = counts[(b*NN + n0 + 1)*2 + 0];
    const int c11 = counts[(b*NN + n0 + 1)*2 + 1];
    const int tA  = c00 + c01, tB = c10 + c11;
    const int tAt = (tA + 15) >> 4, tBt = (tB + 15) >> 4;
    const int tiles = tAt + tBt;
    const int rows  = tiles*16;

    if (tid < TMAX*16) {                 // fill ALL slots (pads: src0, g=4)
        const int r = tid;
        int g = 4, src = 0;
        if (r < tAt*16) {
            if (r < c00)     { src = lists[(b*NN + n0    )*LSTR + r];        g = 0; }
            else if (r < tA) { src = lists[(b*NN + n0 + 1)*LSTR + (r - c00)]; g = 1; }
        } else if (r < rows) {
            const int s = r - tAt*16;
            if (s < c10)     { src = lists[(b*NN + n0    )*LSTR + c00 + s];        g = 2; }
            else if (s < tB) { src = lists[(b*NN + n0 + 1)*LSTR + c01 + (s - c10)]; g = 3; }
        }
        rowinfo_s[r] = src | (g << 8);
    }
    __syncthreads();

    f32x4 acc[TMAX][2];
    #pragma unroll
    for (int q = 0; q < TMAX; ++q) {
        acc[q][0] = (f32x4){0.f, 0.f, 0.f, 0.f};
        acc[q][1] = (f32x4){0.f, 0.f, 0.f, 0.f};
    }

    const float* PQb = PQ + (size_t)b*NN*PQS;
    const int ntb  = nthalf*8 + wave*2;      // this wave's first n-tile
    const int abase = (lane & 15)*ROWB + (lane >> 4)*16;

    #pragma unroll 1
    for (int kt = 0; kt < 8; ++kt) {
        // ---- cooperative A-build: 448 items (row, quad) over 256 threads ----
        #pragma unroll
        for (int pass = 0; pass < 2; ++pass) {
            const int item = tid + pass*256;
            const int row  = item >> 2, quad = item & 3;
            if (row < rows) {
                const int info = rowinfo_s[row];
                const int src  = info & 255;
                const int nd   = (info >> 8) & 1;
                const int tq   = (row >= tAt*16) ? 1 : 0;
                const int cols = kt*32 + quad*8;
                const float* pr = PQb + src*PQS      + tq*512 +       cols;
                const float* qr = PQb + (n0+nd)*PQS  + tq*512 + 256 + cols;
                const float4 Pa = *(const float4*)pr, Pb = *(const float4*)(pr+4);
                const float4 Qa = *(const float4*)qr, Qb = *(const float4*)(qr+4);
                const float u0 = fmaxf(Pa.x + Qa.x, 0.f);
                const float u1 = fmaxf(Pa.y + Qa.y, 0.f);
                const float u2 = fmaxf(Pa.z + Qa.z, 0.f);
                const float u3 = fmaxf(Pa.w + Qa.w, 0.f);
                const float u4 = fmaxf(Pb.x + Qb.x, 0.f);
                const float u5 = fmaxf(Pb.y + Qb.y, 0.f);
                const float u6 = fmaxf(Pb.z + Qb.z, 0.f);
                const float u7 = fmaxf(Pb.w + Qb.w, 0.f);
                const Split3 s0 = split2(u0, u1, PSEL);
                const Split3 s1 = split2(u2, u3, PSEL);
                const Split3 s2 = split2(u4, u5, PSEL);
                const Split3 s3 = split2(u6, u7, PSEL);
                char* w = Apl + row*ROWB + quad*16;
                PackA A0, A1, A2;
                A0.u[0]=s0.d0; A0.u[1]=s1.d0; A0.u[2]=s2.d0; A0.u[3]=s3.d0;
                A1.u[0]=s0.d1; A1.u[1]=s1.d1; A1.u[2]=s2.d1; A1.u[3]=s3.d1;
                A2.u[0]=s0.d2; A2.u[1]=s1.d2; A2.u[2]=s2.d2; A2.u[3]=s3.d2;
                *(short8*)(w)         = A0.s;
                *(short8*)(w + APL)   = A1.s;
                *(short8*)(w + 2*APL) = A2.s;
            }
        }
        __syncthreads();

        // ---- MFMA: all tiles x this wave's 2 n-tiles, A from LDS ----
        #pragma unroll
        for (int sec = 0; sec < 2; ++sec) {
            const int qlo = sec ? tAt : 0;
            const int qhi = sec ? tiles : tAt;
            if (qlo >= qhi) continue;
            short8 Bf[2][3];
            #pragma unroll
            for (int i = 0; i < 2; ++i)
                #pragma unroll
                for (int p = 0; p < 3; ++p)
                    Bf[i][p] = *(const short8*)(W2f + ((size_t)(sec*3+p)*65536
                                 + (size_t)kt*8192 + (size_t)(ntb + i)*512 + (size_t)lane*8));
            #pragma unroll
            for (int q = 0; q < TMAX; ++q) {
                if (q >= qlo && q < qhi) {
                    short8 Af[3];
                    const char* ap = Apl + q*16*ROWB + abase;
                    #pragma unroll
                    for (int p = 0; p < 3; ++p)
                        Af[p] = *(const short8*)(ap + p*APL);
                    #pragma unroll
                    for (int i = 0; i < 2; ++i) {
                        f32x4 a = acc[q][i];
                        a = __builtin_amdgcn_mfma_f32_16x16x32_bf16(Af[2], Bf[i][0], a, 0, 0, 0);
                        a = __builtin_amdgcn_mfma_f32_16x16x32_bf16(Af[1], Bf[i][1], a, 0, 0, 0);
                        a = __builtin_amdgcn_mfma_f32_16x16x32_bf16(Af[0], Bf[i][2], a, 0, 0, 0);
                        a = __builtin_amdgcn_mfma_f32_16x16x32_bf16(Af[1], Bf[i][0], a, 0, 0, 0);
                        a = __builtin_amdgcn_mfma_f32_16x16x32_bf16(Af[0], Bf[i][1], a, 0, 0, 0);
                        a = __builtin_amdgcn_mfma_f32_16x16x32_bf16(Af[0], Bf[i][0], a, 0, 0, 0);
                        acc[q][i] = a;
                    }
                }
            }
        }
        __syncthreads();
    }

    // ---- readout: relu(acc+b2), per-row node mask, shfl-reduce, store ----
    float b2v[2][2];
    #pragma unroll
    for (int t = 0; t < 2; ++t)
        #pragma unroll
        for (int i = 0; i < 2; ++i)
            b2v[t][i] = b2[t*HH + (ntb + i)*16 + (lane & 15)];

    float p0[2], p1[2];
    p0[0] = p0[1] = p1[0] = p1[1] = 0.f;
    #pragma unroll
    for (int q = 0; q < TMAX; ++q) {
        if (q < tiles) {
            const bool secB = (q >= tAt);
            int gv[4];
            #pragma unroll
            for (int rr = 0; rr < 4; ++rr)
                gv[rr] = rowinfo_s[q*16 + (lane >> 4)*4 + rr] >> 8;
            #pragma unroll
            for (int i = 0; i < 2; ++i) {
                const float bias = secB ? b2v[1][i] : b2v[0][i];
                #pragma unroll
                for (int rr = 0; rr < 4; ++rr) {
                    const float v = fmaxf(acc[q][i][rr] + bias, 0.f);
                    const bool valid = gv[rr] < 4;
                    p0[i] += (valid && !(gv[rr] & 1)) ? v : 0.f;
                    p1[i] += (valid &&  (gv[rr] & 1)) ? v : 0.f;
                }
            }
        }
    }
    #pragma unroll
    for (int i = 0; i < 2; ++i) {
        float v0 = p0[i], v1 = p1[i];
        v0 += __shfl_xor(v0, 16); v0 += __shfl_xor(v0, 32);
        v1 += __shfl_xor(v1, 16); v1 += __shfl_xor(v1, 32);
        if ((lane >> 4) == 0) {
            node_msg[((size_t)(b*NN + n0  ))*HH + (ntb + i)*16 + lane] = v0;
            node_msg[((size_t)(b*NN + n0+1))*HH + (ntb + i)*16 + lane] = v1;
        }
    }
}

// ---------------------------------------------------------------------------
// Decoder: 4 rows/block (384 blocks), XCD-clustered, single node_msg,
// fused next-step PQ production.
// ---------------------------------------------------------------------------
__global__ __launch_bounds__(256, 2) void k_dec(
    float* __restrict__ state,
    const float* __restrict__ nm,
    const float* __restrict__ W1, const float* __restrict__ b1,   // (272,256)
    const float* __restrict__ W2, const float* __restrict__ b2,   // (256,256)
    const float* __restrict__ W3, const float* __restrict__ b3,   // (256,16)
    const float* __restrict__ eW1T,  // (2,256,32)
    const float* __restrict__ eb1,   // (2,256)
    float* __restrict__ PQ,
    float* __restrict__ out, int step)
{
    const int lb   = (blockIdx.x & 7)*48 + (blockIdx.x >> 3);
    const int b    = lb / 12;
    const int row0 = (lb % 12) * 4;
    const int c    = threadIdx.x;

    __shared__ float in_s[4][272];
    __shared__ float d1s[4][HH];
    __shared__ float stn[4][DD];

    for (int i = c; i < 4*272; i += 256) {
        const int m = i / 272, k = i % 272;
        const int r = row0 + m;
        in_s[m][k] = (k < DD)
            ? state[((size_t)b*NN + r)*DD + k]
            : nm[((size_t)b*NN + r)*HH + (k - DD)];
    }
    __syncthreads();

    float a0[4];
    {
        const float bb = b1[c];
        #pragma unroll
        for (int m = 0; m < 4; ++m) a0[m] = bb;
        #pragma unroll 2
        for (int k4 = 0; k4 < 68; ++k4) {
            const float* wr = W1 + (k4*4)*HH;
            const float w0=wr[c], w1_=wr[HH+c], w2_=wr[2*HH+c], w3=wr[3*HH+c];
            #pragma unroll
            for (int m = 0; m < 4; ++m) {
                const float4 h = *(const float4*)&in_s[m][k4*4];
                a0[m] = fmaf(h.x,w0, fmaf(h.y,w1_, fmaf(h.z,w2_, fmaf(h.w,w3, a0[m]))));
            }
        }
        #pragma unroll
        for (int m = 0; m < 4; ++m) d1s[m][c] = fmaxf(a0[m], 0.f);
    }
    __syncthreads();
    {
        const float bb = b2[c];
        #pragma unroll
        for (int m = 0; m < 4; ++m) a0[m] = bb;
        #pragma unroll 2
        for (int k4 = 0; k4 < 64; ++k4) {
            const float* wr = W2 + (k4*4)*HH;
            const float w0=wr[c], w1_=wr[HH+c], w2_=wr[2*HH+c], w3=wr[3*HH+c];
            #pragma unroll
            for (int m = 0; m < 4; ++m) {
                const float4 h = *(const float4*)&d1s[m][k4*4];
                a0[m] = fmaf(h.x,w0, fmaf(h.y,w1_, fmaf(h.z,w2_, fmaf(h.w,w3, a0[m]))));
            }
        }
        __syncthreads();
        #pragma unroll
        for (int m = 0; m < 4; ++m) in_s[m][c] = fmaxf(a0[m], 0.f);
    }
    __syncthreads();
    if (c < 64) {
        const int m = c >> 4, cc = c & 15;
        float a = b3[cc];
        #pragma unroll 4
        for (int k4 = 0; k4 < 64; ++k4) {
            const float4 h = *(const float4*)&in_s[m][k4*4];
            a += h.x*W3[(k4*4+0)*16+cc] + h.y*W3[(k4*4+1)*16+cc]
               + h.z*W3[(k4*4+2)*16+cc] + h.w*W3[(k4*4+3)*16+cc];
        }
        const int r = row0 + m;
        const float v = state[((size_t)b*NN + r)*DD + cc] + a;
        state[((size_t)b*NN + r)*DD + cc] = v;
        out[(((size_t)b*NPRED + step)*NN + r)*DD + cc] = v;
        stn[m][cc] = v;
    }
    __syncthreads();
    float4 sm[4][4];
    #pragma unroll
    for (int m = 0; m < 4; ++m)
        #pragma unroll
        for (int f4 = 0; f4 < 4; ++f4)
            sm[m][f4] = *(const float4*)&stn[m][f4*4];
    #pragma unroll
    for (int k = 0; k < 4; ++k) {
        const int combo = c + 256*k;
        const int cc = combo & 255;
        const int pq = (combo >> 8) & 1;
        const int t  = combo >> 9;
        const float* wc = eW1T + ((size_t)t*HH + cc)*32 + pq*16;
        float4 w[4];
        #pragma unroll
        for (int f4 = 0; f4 < 4; ++f4) w[f4] = ((const float4*)wc)[f4];
        const float bias = pq ? eb1[t*HH + cc] : 0.f;
        #pragma unroll
        for (int m = 0; m < 4; ++m) {
            float v = bias;
            #pragma unroll
            for (int f4 = 0; f4 < 4; ++f4) {
                const float4 s = sm[m][f4];
                v = fmaf(s.x,w[f4].x, fmaf(s.y,w[f4].y, fmaf(s.z,w[f4].z, fmaf(s.w,w[f4].w, v))));
            }
            PQ[(size_t)(b*NN + row0 + m)*PQS + t*512 + pq*256 + cc] = v;
        }
    }
}

// ---------------------------------------------------------------------------
extern "C" void kernel_launch(void* const* d_in, const int* in_sizes, int n_in,
                              void* d_out, int out_size, void* d_ws, size_t ws_size,
                              hipStream_t stream)
{
    const float* time_segs  = (const float*)d_in[0];
    const float* edge_types = (const float*)d_in[1];
    const float* enc_W1 = (const float*)d_in[4];
    const float* enc_b1 = (const float*)d_in[5];
    const float* enc_W2 = (const float*)d_in[6];
    const float* enc_b2 = (const float*)d_in[7];
    const float* dec_W1 = (const float*)d_in[8];
    const float* dec_b1 = (const float*)d_in[9];
    const float* dec_W2 = (const float*)d_in[10];
    const float* dec_b2 = (const float*)d_in[11];
    const float* out_W  = (const float*)d_in[12];
    const float* out_b  = (const float*)d_in[13];
    float* out = (float*)d_out;

    // workspace (~9.3 MB)
    float* state    = (float*)d_ws;                    // 24576 f
    float* node_msg = state + BB*NN*DD;                // 393216 f
    float* W1T      = node_msg + BB*NN*HH;             // 16384 f
    unsigned short* W2f = (unsigned short*)(W1T + 2*HH*32);   // 393216 us
    int*   lists    = (int*)(W2f + 2*3*65536);         // 86016 i
    int*   counts   = lists + BB*NN*LSTR;              // 3072 i
    float* PQ       = (float*)(counts + BB*NN*2);      // 1597440 f

    k_setup<<<192, 256, 0, stream>>>(time_segs, edge_types, enc_W1, enc_W2,
                                     enc_b1, state, W1T, W2f, PQ, lists, counts);
    for (int stp = 0; stp < NPRED; ++stp) {
        k_enc<<<BB*NN, 256, 0, stream>>>(lists, counts, PQ, W2f,
                                         enc_b2, node_msg);
        k_dec<<<BB*12, 256, 0, stream>>>(state, node_msg,
                                         dec_W1, dec_b1, dec_W2, dec_b2,
                                         out_W, out_b, W1T, enc_b1, PQ, out, stp);
    }
}

// Round 19
// 628.089 us; speedup vs baseline: 1.1670x; 1.0070x over previous
//
#include <hip/hip_runtime.h>

#define NN    48
#define DD    16
#define HH    256
#define EE    2256
#define BB    32
#define NPRED 8
#define LSTR  56
#define PQS   1040                   // PQ per-node stride (floats), de-pow2
#define TMAX  7                      // packed tiles/pair <= 7 (tA+tB<=94)
#define ROWB  80                     // A-plane row stride bytes (5x16B, 2-way banks)
#define APL   (TMAX*16*ROWB)         // 8960 B per plane

typedef __attribute__((ext_vector_type(4))) float f32x4;
typedef __attribute__((ext_vector_type(8))) short short8;

__device__ __forceinline__ float bf2f(unsigned short h) {
    union { unsigned u; float f; } v; v.u = ((unsigned)h) << 16; return v.f;
}
__device__ __forceinline__ unsigned short f2bf(float x) {
    union { float f; unsigned u; } v; v.f = x;
    unsigned r = v.u + 0x7fffu + ((v.u >> 16) & 1u);
    return (unsigned short)(r >> 16);
}
__device__ __forceinline__ unsigned perm_hi16(unsigned xB, unsigned xA, unsigned sel) {
    unsigned d;
    asm("v_perm_b32 %0, %1, %2, %3" : "=v"(d) : "v"(xB), "v"(xA), "s"(sel));
    return d;
}
struct Split3 { unsigned d0, d1, d2; };
__device__ __forceinline__ Split3 split2(float u0, float u1, unsigned sel)
{
    union F { float f; unsigned u; };
    Split3 o;
    F x0, x1; x0.f = u0; x1.f = u1;
    o.d0 = perm_hi16(x1.u, x0.u, sel);
    F h0a, h0b; h0a.u = x0.u & 0xffff0000u; h0b.u = x1.u & 0xffff0000u;
    F e0a, e0b; e0a.f = u0 - h0a.f; e0b.f = u1 - h0b.f;
    o.d1 = perm_hi16(e0b.u, e0a.u, sel);
    F h1a, h1b; h1a.u = e0a.u & 0xffff0000u; h1b.u = e0b.u & 0xffff0000u;
    F e1a, e1b; e1a.f = e0a.f - h1a.f; e1b.f = e0b.f - h1b.f;
    o.d2 = perm_hi16(e1b.u, e1a.u, sel);
    return o;
}
union PackA { unsigned u[4]; short8 s; };

// ---------------------------------------------------------------------------
// Setup (384 blocks — was latency-bound at 192).
// ---------------------------------------------------------------------------
__global__ __launch_bounds__(256) void k_setup(
    const float* __restrict__ time_segs,
    const float* __restrict__ edge_types,
    const float* __restrict__ W1,      // (2,32,256)
    const float* __restrict__ W2,      // (2,256,256)
    const float* __restrict__ b1,      // (2,256)
    float* __restrict__ state,
    float* __restrict__ W1T,           // (2,256,32)
    unsigned short* __restrict__ W2f,  // 393216
    float* __restrict__ PQ,
    int* __restrict__ lists,
    int* __restrict__ counts)
{
    const int tid = blockIdx.x * 256 + threadIdx.x;
    const int NT = 384*256;
    for (int i = tid; i < BB*NN*DD; i += NT)
        state[i] = time_segs[i];
    for (int i = tid; i < 2*HH*32; i += NT) {
        const int t = i >> 13, r = i & 8191, h = r >> 5, f = r & 31;
        W1T[i] = W1[(t*32 + f)*HH + h];
    }
    for (int i = tid; i < 2*8*16*64*8; i += NT) {
        const int j  = i & 7, l = (i >> 3) & 63, nt = (i >> 9) & 15;
        const int kt = (i >> 13) & 7, t = (i >> 16) & 1;
        const int k = kt*32 + ((l >> 4) << 3) + j;
        const int n = nt*16 + (l & 15);
        const float w = W2[((size_t)t*HH + k)*HH + n];
        const unsigned short h0 = f2bf(w);  const float r1 = w  - bf2f(h0);
        const unsigned short h1 = f2bf(r1); const float r2 = r1 - bf2f(h1);
        const unsigned short h2 = f2bf(r2);
        const size_t rest = (size_t)kt*8192 + nt*512 + l*8 + j;
        W2f[(size_t)(t*3+0)*65536 + rest] = h0;
        W2f[(size_t)(t*3+1)*65536 + rest] = h1;
        W2f[(size_t)(t*3+2)*65536 + rest] = h2;
    }
    for (int i = tid; i < BB*NN*1024; i += NT) {
        const int c  = i & 255;
        const int pq = (i >> 8) & 1;
        const int t  = (i >> 9) & 1;
        const int nb = i >> 10;
        float v = pq ? b1[t*HH + c] : 0.f;
        #pragma unroll
        for (int f = 0; f < DD; ++f)
            v = fmaf(time_segs[nb*DD + f], W1[(t*32 + pq*16 + f)*HH + c], v);
        PQ[(size_t)nb*PQS + (i & 1023)] = v;
    }
    if (tid < BB*NN) {
        const int b = tid / NN;
        const int n = tid % NN;
        int* lst = lists + tid * LSTR;
        int c = 0;
        for (int s = 0; s < NN; ++s) {
            if (s == n) continue;
            const int e = s * 47 + (n > s ? n - 1 : n);
            if (edge_types[((size_t)b*EE + e)*3 + 1] > 0.5f) lst[c++] = s;
        }
        const int c1 = c;
        for (int s = 0; s < NN; ++s) {
            if (s == n) continue;
            const int e = s * 47 + (n > s ? n - 1 : n);
            if (edge_types[((size_t)b*EE + e)*3 + 2] > 0.5f) lst[c++] = s;
        }
        counts[tid*2 + 0] = c1;
        counts[tid*2 + 1] = c - c1;
        for (int i = c; i < LSTR; ++i) lst[i] = 0;
    }
}

// ---------------------------------------------------------------------------
// Encoder v10b: block = (pair, nt-half), 4 waves. A-planes built ONCE per
// block into LDS, each wave MFMAs all tiles x its 2 n-tiles from LDS.
// launch_bounds(256,4): 4 blocks/CU (112 unified regs <= 128, LDS 110KB)
// so build/MFMA phases of different blocks overlap across barriers.
// ---------------------------------------------------------------------------
__global__ __launch_bounds__(256, 4) void k_enc(
    const int*   __restrict__ lists,
    const int*   __restrict__ counts,
    const float* __restrict__ PQ,
    const unsigned short* __restrict__ W2f,
    const float* __restrict__ b2,    // (2,256)
    float* __restrict__ node_msg)
{
    const int lb     = (blockIdx.x & 7)*192 + (blockIdx.x >> 3);  // XCD cluster
    const int b      = lb / 48;          // 4 batches per XCD
    const int rem    = lb % 48;
    const int pair   = rem >> 1;
    const int nthalf = rem & 1;
    const int n0     = pair * 2;
    const int tid    = threadIdx.x;
    const int lane   = tid & 63, wave = tid >> 6;
    const unsigned PSEL = 0x07060302u;

    __shared__ __align__(16) char Apl[3*APL];   // 26.9 KB
    __shared__ int rowinfo_s[TMAX*16];

    const int c00 = counts[(b*NN + n0    )*2 + 0];
    const int c10 = counts[(b*NN + n0    )*2 + 1];
    const int c01 = counts[(b*NN + n0 + 1)*2 + 0];
    const int c11 = counts[(b*NN + n0 + 1)*2 + 1];
    const int tA  = c00 + c01, tB = c10 + c11;
    const int tAt = (tA + 15) >> 4, tBt = (tB + 15) >> 4;
    const int tiles = tAt + tBt;
    const int rows  = tiles*16;

    if (tid < TMAX*16) {                 // fill ALL slots (pads: src0, g=4)
        const int r = tid;
        int g = 4, src = 0;
        if (r < tAt*16) {
            if (r < c00)     { src = lists[(b*NN + n0    )*LSTR + r];        g = 0; }
            else if (r < tA) { src = lists[(b*NN + n0 + 1)*LSTR + (r - c00)]; g = 1; }
        } else if (r < rows) {
            const int s = r - tAt*16;
            if (s < c10)     { src = lists[(b*NN + n0    )*LSTR + c00 + s];        g = 2; }
            else if (s < tB) { src = lists[(b*NN + n0 + 1)*LSTR + c01 + (s - c10)]; g = 3; }
        }
        rowinfo_s[r] = src | (g << 8);
    }
    __syncthreads();

    f32x4 acc[TMAX][2];
    #pragma unroll
    for (int q = 0; q < TMAX; ++q) {
        acc[q][0] = (f32x4){0.f, 0.f, 0.f, 0.f};
        acc[q][1] = (f32x4){0.f, 0.f, 0.f, 0.f};
    }

    const float* PQb = PQ + (size_t)b*NN*PQS;
    const int ntb  = nthalf*8 + wave*2;      // this wave's first n-tile
    const int abase = (lane & 15)*ROWB + (lane >> 4)*16;

    #pragma unroll 1
    for (int kt = 0; kt < 8; ++kt) {
        // ---- cooperative A-build: 448 items (row, quad) over 256 threads ----
        #pragma unroll
        for (int pass = 0; pass < 2; ++pass) {
            const int item = tid + pass*256;
            const int row  = item >> 2, quad = item & 3;
            if (row < rows) {
                const int info = rowinfo_s[row];
                const int src  = info & 255;
                const int nd   = (info >> 8) & 1;
                const int tq   = (row >= tAt*16) ? 1 : 0;
                const int cols = kt*32 + quad*8;
                const float* pr = PQb + src*PQS      + tq*512 +       cols;
                const float* qr = PQb + (n0+nd)*PQS  + tq*512 + 256 + cols;
                const float4 Pa = *(const float4*)pr, Pb = *(const float4*)(pr+4);
                const float4 Qa = *(const float4*)qr, Qb = *(const float4*)(qr+4);
                const float u0 = fmaxf(Pa.x + Qa.x, 0.f);
                const float u1 = fmaxf(Pa.y + Qa.y, 0.f);
                const float u2 = fmaxf(Pa.z + Qa.z, 0.f);
                const float u3 = fmaxf(Pa.w + Qa.w, 0.f);
                const float u4 = fmaxf(Pb.x + Qb.x, 0.f);
                const float u5 = fmaxf(Pb.y + Qb.y, 0.f);
                const float u6 = fmaxf(Pb.z + Qb.z, 0.f);
                const float u7 = fmaxf(Pb.w + Qb.w, 0.f);
                const Split3 s0 = split2(u0, u1, PSEL);
                const Split3 s1 = split2(u2, u3, PSEL);
                const Split3 s2 = split2(u4, u5, PSEL);
                const Split3 s3 = split2(u6, u7, PSEL);
                char* w = Apl + row*ROWB + quad*16;
                PackA A0, A1, A2;
                A0.u[0]=s0.d0; A0.u[1]=s1.d0; A0.u[2]=s2.d0; A0.u[3]=s3.d0;
                A1.u[0]=s0.d1; A1.u[1]=s1.d1; A1.u[2]=s2.d1; A1.u[3]=s3.d1;
                A2.u[0]=s0.d2; A2.u[1]=s1.d2; A2.u[2]=s2.d2; A2.u[3]=s3.d2;
                *(short8*)(w)         = A0.s;
                *(short8*)(w + APL)   = A1.s;
                *(short8*)(w + 2*APL) = A2.s;
            }
        }
        __syncthreads();

        // ---- MFMA: all tiles x this wave's 2 n-tiles, A from LDS ----
        #pragma unroll
        for (int sec = 0; sec < 2; ++sec) {
            const int qlo = sec ? tAt : 0;
            const int qhi = sec ? tiles : tAt;
            if (qlo >= qhi) continue;
            short8 Bf[2][3];
            #pragma unroll
            for (int i = 0; i < 2; ++i)
                #pragma unroll
                for (int p = 0; p < 3; ++p)
                    Bf[i][p] = *(const short8*)(W2f + ((size_t)(sec*3+p)*65536
                                 + (size_t)kt*8192 + (size_t)(ntb + i)*512 + (size_t)lane*8));
            #pragma unroll
            for (int q = 0; q < TMAX; ++q) {
                if (q >= qlo && q < qhi) {
                    short8 Af[3];
                    const char* ap = Apl + q*16*ROWB + abase;
                    #pragma unroll
                    for (int p = 0; p < 3; ++p)
                        Af[p] = *(const short8*)(ap + p*APL);
                    #pragma unroll
                    for (int i = 0; i < 2; ++i) {
                        f32x4 a = acc[q][i];
                        a = __builtin_amdgcn_mfma_f32_16x16x32_bf16(Af[2], Bf[i][0], a, 0, 0, 0);
                        a = __builtin_amdgcn_mfma_f32_16x16x32_bf16(Af[1], Bf[i][1], a, 0, 0, 0);
                        a = __builtin_amdgcn_mfma_f32_16x16x32_bf16(Af[0], Bf[i][2], a, 0, 0, 0);
                        a = __builtin_amdgcn_mfma_f32_16x16x32_bf16(Af[1], Bf[i][0], a, 0, 0, 0);
                        a = __builtin_amdgcn_mfma_f32_16x16x32_bf16(Af[0], Bf[i][1], a, 0, 0, 0);
                        a = __builtin_amdgcn_mfma_f32_16x16x32_bf16(Af[0], Bf[i][0], a, 0, 0, 0);
                        acc[q][i] = a;
                    }
                }
            }
        }
        __syncthreads();
    }

    // ---- readout: relu(acc+b2), per-row node mask, shfl-reduce, store ----
    float b2v[2][2];
    #pragma unroll
    for (int t = 0; t < 2; ++t)
        #pragma unroll
        for (int i = 0; i < 2; ++i)
            b2v[t][i] = b2[t*HH + (ntb + i)*16 + (lane & 15)];

    float p0[2], p1[2];
    p0[0] = p0[1] = p1[0] = p1[1] = 0.f;
    #pragma unroll
    for (int q = 0; q < TMAX; ++q) {
        if (q < tiles) {
            const bool secB = (q >= tAt);
            int gv[4];
            #pragma unroll
            for (int rr = 0; rr < 4; ++rr)
                gv[rr] = rowinfo_s[q*16 + (lane >> 4)*4 + rr] >> 8;
            #pragma unroll
            for (int i = 0; i < 2; ++i) {
                const float bias = secB ? b2v[1][i] : b2v[0][i];
                #pragma unroll
                for (int rr = 0; rr < 4; ++rr) {
                    const float v = fmaxf(acc[q][i][rr] + bias, 0.f);
                    const bool valid = gv[rr] < 4;
                    p0[i] += (valid && !(gv[rr] & 1)) ? v : 0.f;
                    p1[i] += (valid &&  (gv[rr] & 1)) ? v : 0.f;
                }
            }
        }
    }
    #pragma unroll
    for (int i = 0; i < 2; ++i) {
        float v0 = p0[i], v1 = p1[i];
        v0 += __shfl_xor(v0, 16); v0 += __shfl_xor(v0, 32);
        v1 += __shfl_xor(v1, 16); v1 += __shfl_xor(v1, 32);
        if ((lane >> 4) == 0) {
            node_msg[((size_t)(b*NN + n0  ))*HH + (ntb + i)*16 + lane] = v0;
            node_msg[((size_t)(b*NN + n0+1))*HH + (ntb + i)*16 + lane] = v1;
        }
    }
}

// ---------------------------------------------------------------------------
// Decoder: 4 rows/block (384 blocks), XCD-clustered, single node_msg,
// fused next-step PQ production. Unchanged.
// ---------------------------------------------------------------------------
__global__ __launch_bounds__(256, 2) void k_dec(
    float* __restrict__ state,
    const float* __restrict__ nm,
    const float* __restrict__ W1, const float* __restrict__ b1,   // (272,256)
    const float* __restrict__ W2, const float* __restrict__ b2,   // (256,256)
    const float* __restrict__ W3, const float* __restrict__ b3,   // (256,16)
    const float* __restrict__ eW1T,  // (2,256,32)
    const float* __restrict__ eb1,   // (2,256)
    float* __restrict__ PQ,
    float* __restrict__ out, int step)
{
    const int lb   = (blockIdx.x & 7)*48 + (blockIdx.x >> 3);
    const int b    = lb / 12;
    const int row0 = (lb % 12) * 4;
    const int c    = threadIdx.x;

    __shared__ float in_s[4][272];
    __shared__ float d1s[4][HH];
    __shared__ float stn[4][DD];

    for (int i = c; i < 4*272; i += 256) {
        const int m = i / 272, k = i % 272;
        const int r = row0 + m;
        in_s[m][k] = (k < DD)
            ? state[((size_t)b*NN + r)*DD + k]
            : nm[((size_t)b*NN + r)*HH + (k - DD)];
    }
    __syncthreads();

    float a0[4];
    {
        const float bb = b1[c];
        #pragma unroll
        for (int m = 0; m < 4; ++m) a0[m] = bb;
        #pragma unroll 2
        for (int k4 = 0; k4 < 68; ++k4) {
            const float* wr = W1 + (k4*4)*HH;
            const float w0=wr[c], w1_=wr[HH+c], w2_=wr[2*HH+c], w3=wr[3*HH+c];
            #pragma unroll
            for (int m = 0; m < 4; ++m) {
                const float4 h = *(const float4*)&in_s[m][k4*4];
                a0[m] = fmaf(h.x,w0, fmaf(h.y,w1_, fmaf(h.z,w2_, fmaf(h.w,w3, a0[m]))));
            }
        }
        #pragma unroll
        for (int m = 0; m < 4; ++m) d1s[m][c] = fmaxf(a0[m], 0.f);
    }
    __syncthreads();
    {
        const float bb = b2[c];
        #pragma unroll
        for (int m = 0; m < 4; ++m) a0[m] = bb;
        #pragma unroll 2
        for (int k4 = 0; k4 < 64; ++k4) {
            const float* wr = W2 + (k4*4)*HH;
            const float w0=wr[c], w1_=wr[HH+c], w2_=wr[2*HH+c], w3=wr[3*HH+c];
            #pragma unroll
            for (int m = 0; m < 4; ++m) {
                const float4 h = *(const float4*)&d1s[m][k4*4];
                a0[m] = fmaf(h.x,w0, fmaf(h.y,w1_, fmaf(h.z,w2_, fmaf(h.w,w3, a0[m]))));
            }
        }
        __syncthreads();
        #pragma unroll
        for (int m = 0; m < 4; ++m) in_s[m][c] = fmaxf(a0[m], 0.f);
    }
    __syncthreads();
    if (c < 64) {
        const int m = c >> 4, cc = c & 15;
        float a = b3[cc];
        #pragma unroll 4
        for (int k4 = 0; k4 < 64; ++k4) {
            const float4 h = *(const float4*)&in_s[m][k4*4];
            a += h.x*W3[(k4*4+0)*16+cc] + h.y*W3[(k4*4+1)*16+cc]
               + h.z*W3[(k4*4+2)*16+cc] + h.w*W3[(k4*4+3)*16+cc];
        }
        const int r = row0 + m;
        const float v = state[((size_t)b*NN + r)*DD + cc] + a;
        state[((size_t)b*NN + r)*DD + cc] = v;
        out[(((size_t)b*NPRED + step)*NN + r)*DD + cc] = v;
        stn[m][cc] = v;
    }
    __syncthreads();
    float4 sm[4][4];
    #pragma unroll
    for (int m = 0; m < 4; ++m)
        #pragma unroll
        for (int f4 = 0; f4 < 4; ++f4)
            sm[m][f4] = *(const float4*)&stn[m][f4*4];
    #pragma unroll
    for (int k = 0; k < 4; ++k) {
        const int combo = c + 256*k;
        const int cc = combo & 255;
        const int pq = (combo >> 8) & 1;
        const int t  = combo >> 9;
        const float* wc = eW1T + ((size_t)t*HH + cc)*32 + pq*16;
        float4 w[4];
        #pragma unroll
        for (int f4 = 0; f4 < 4; ++f4) w[f4] = ((const float4*)wc)[f4];
        const float bias = pq ? eb1[t*HH + cc] : 0.f;
        #pragma unroll
        for (int m = 0; m < 4; ++m) {
            float v = bias;
            #pragma unroll
            for (int f4 = 0; f4 < 4; ++f4) {
                const float4 s = sm[m][f4];
                v = fmaf(s.x,w[f4].x, fmaf(s.y,w[f4].y, fmaf(s.z,w[f4].z, fmaf(s.w,w[f4].w, v))));
            }
            PQ[(size_t)(b*NN + row0 + m)*PQS + t*512 + pq*256 + cc] = v;
        }
    }
}

// ---------------------------------------------------------------------------
extern "C" void kernel_launch(void* const* d_in, const int* in_sizes, int n_in,
                              void* d_out, int out_size, void* d_ws, size_t ws_size,
                              hipStream_t stream)
{
    const float* time_segs  = (const float*)d_in[0];
    const float* edge_types = (const float*)d_in[1];
    const float* enc_W1 = (const float*)d_in[4];
    const float* enc_b1 = (const float*)d_in[5];
    const float* enc_W2 = (const float*)d_in[6];
    const float* enc_b2 = (const float*)d_in[7];
    const float* dec_W1 = (const float*)d_in[8];
    const float* dec_b1 = (const float*)d_in[9];
    const float* dec_W2 = (const float*)d_in[10];
    const float* dec_b2 = (const float*)d_in[11];
    const float* out_W  = (const float*)d_in[12];
    const float* out_b  = (const float*)d_in[13];
    float* out = (float*)d_out;

    // workspace (~9.3 MB)
    float* state    = (float*)d_ws;                    // 24576 f
    float* node_msg = state + BB*NN*DD;                // 393216 f
    float* W1T      = node_msg + BB*NN*HH;             // 16384 f
    unsigned short* W2f = (unsigned short*)(W1T + 2*HH*32);   // 393216 us
    int*   lists    = (int*)(W2f + 2*3*65536);         // 86016 i
    int*   counts   = lists + BB*NN*LSTR;              // 3072 i
    float* PQ       = (float*)(counts + BB*NN*2);      // 1597440 f

    k_setup<<<384, 256, 0, stream>>>(time_segs, edge_types, enc_W1, enc_W2,
                                     enc_b1, state, W1T, W2f, PQ, lists, counts);
    for (int stp = 0; stp < NPRED; ++stp) {
        k_enc<<<BB*NN, 256, 0, stream>>>(lists, counts, PQ, W2f,
                                         enc_b2, node_msg);
        k_dec<<<BB*12, 256, 0, stream>>>(state, node_msg,
                                         dec_W1, dec_b1, dec_W2, dec_b2,
                                         out_W, out_b, W1T, enc_b1, PQ, out, stp);
    }
}

// Round 20
// 615.260 us; speedup vs baseline: 1.1914x; 1.0209x over previous
//
#include <hip/hip_runtime.h>

#define NN    48
#define DD    16
#define HH    256
#define EE    2256
#define BB    32
#define NPRED 8
#define LSTR  56
#define PQS   1040                   // PQ per-node stride (floats), de-pow2
#define TMAX  7                      // packed tiles/pair <= 7 (tA+tB<=94)
#define ROWB  80                     // A-plane row stride bytes (5x16B, 2-way banks)
#define APL   (TMAX*16*ROWB)         // 8960 B per plane

typedef __attribute__((ext_vector_type(4))) float f32x4;
typedef __attribute__((ext_vector_type(8))) short short8;

__device__ __forceinline__ float bf2f(unsigned short h) {
    union { unsigned u; float f; } v; v.u = ((unsigned)h) << 16; return v.f;
}
__device__ __forceinline__ unsigned short f2bf(float x) {
    union { float f; unsigned u; } v; v.f = x;
    unsigned r = v.u + 0x7fffu + ((v.u >> 16) & 1u);
    return (unsigned short)(r >> 16);
}
__device__ __forceinline__ unsigned perm_hi16(unsigned xB, unsigned xA, unsigned sel) {
    unsigned d;
    asm("v_perm_b32 %0, %1, %2, %3" : "=v"(d) : "v"(xB), "v"(xA), "s"(sel));
    return d;
}
struct Split3 { unsigned d0, d1, d2; };
__device__ __forceinline__ Split3 split2(float u0, float u1, unsigned sel)
{
    union F { float f; unsigned u; };
    Split3 o;
    F x0, x1; x0.f = u0; x1.f = u1;
    o.d0 = perm_hi16(x1.u, x0.u, sel);
    F h0a, h0b; h0a.u = x0.u & 0xffff0000u; h0b.u = x1.u & 0xffff0000u;
    F e0a, e0b; e0a.f = u0 - h0a.f; e0b.f = u1 - h0b.f;
    o.d1 = perm_hi16(e0b.u, e0a.u, sel);
    F h1a, h1b; h1a.u = e0a.u & 0xffff0000u; h1b.u = e0b.u & 0xffff0000u;
    F e1a, e1b; e1a.f = e0a.f - h1a.f; e1b.f = e0b.f - h1b.f;
    o.d2 = perm_hi16(e1b.u, e1a.u, sel);
    return o;
}
union PackA { unsigned u[4]; short8 s; };

// ---------------------------------------------------------------------------
// Setup (384 blocks).
// ---------------------------------------------------------------------------
__global__ __launch_bounds__(256) void k_setup(
    const float* __restrict__ time_segs,
    const float* __restrict__ edge_types,
    const float* __restrict__ W1,      // (2,32,256)
    const float* __restrict__ W2,      // (2,256,256)
    const float* __restrict__ b1,      // (2,256)
    float* __restrict__ state,
    float* __restrict__ W1T,           // (2,256,32)
    unsigned short* __restrict__ W2f,  // 393216
    float* __restrict__ PQ,
    int* __restrict__ lists,
    int* __restrict__ counts)
{
    const int tid = blockIdx.x * 256 + threadIdx.x;
    const int NT = 384*256;
    for (int i = tid; i < BB*NN*DD; i += NT)
        state[i] = time_segs[i];
    for (int i = tid; i < 2*HH*32; i += NT) {
        const int t = i >> 13, r = i & 8191, h = r >> 5, f = r & 31;
        W1T[i] = W1[(t*32 + f)*HH + h];
    }
    for (int i = tid; i < 2*8*16*64*8; i += NT) {
        const int j  = i & 7, l = (i >> 3) & 63, nt = (i >> 9) & 15;
        const int kt = (i >> 13) & 7, t = (i >> 16) & 1;
        const int k = kt*32 + ((l >> 4) << 3) + j;
        const int n = nt*16 + (l & 15);
        const float w = W2[((size_t)t*HH + k)*HH + n];
        const unsigned short h0 = f2bf(w);  const float r1 = w  - bf2f(h0);
        const unsigned short h1 = f2bf(r1); const float r2 = r1 - bf2f(h1);
        const unsigned short h2 = f2bf(r2);
        const size_t rest = (size_t)kt*8192 + nt*512 + l*8 + j;
        W2f[(size_t)(t*3+0)*65536 + rest] = h0;
        W2f[(size_t)(t*3+1)*65536 + rest] = h1;
        W2f[(size_t)(t*3+2)*65536 + rest] = h2;
    }
    for (int i = tid; i < BB*NN*1024; i += NT) {
        const int c  = i & 255;
        const int pq = (i >> 8) & 1;
        const int t  = (i >> 9) & 1;
        const int nb = i >> 10;
        float v = pq ? b1[t*HH + c] : 0.f;
        #pragma unroll
        for (int f = 0; f < DD; ++f)
            v = fmaf(time_segs[nb*DD + f], W1[(t*32 + pq*16 + f)*HH + c], v);
        PQ[(size_t)nb*PQS + (i & 1023)] = v;
    }
    if (tid < BB*NN) {
        const int b = tid / NN;
        const int n = tid % NN;
        int* lst = lists + tid * LSTR;
        int c = 0;
        for (int s = 0; s < NN; ++s) {
            if (s == n) continue;
            const int e = s * 47 + (n > s ? n - 1 : n);
            if (edge_types[((size_t)b*EE + e)*3 + 1] > 0.5f) lst[c++] = s;
        }
        const int c1 = c;
        for (int s = 0; s < NN; ++s) {
            if (s == n) continue;
            const int e = s * 47 + (n > s ? n - 1 : n);
            if (edge_types[((size_t)b*EE + e)*3 + 2] > 0.5f) lst[c++] = s;
        }
        counts[tid*2 + 0] = c1;
        counts[tid*2 + 1] = c - c1;
        for (int i = c; i < LSTR; ++i) lst[i] = 0;
    }
}

#define MFMA6(Ax, Bi, a)                                                       \
    a = __builtin_amdgcn_mfma_f32_16x16x32_bf16(Ax[2], Bi[0], a, 0, 0, 0);     \
    a = __builtin_amdgcn_mfma_f32_16x16x32_bf16(Ax[1], Bi[1], a, 0, 0, 0);     \
    a = __builtin_amdgcn_mfma_f32_16x16x32_bf16(Ax[0], Bi[2], a, 0, 0, 0);     \
    a = __builtin_amdgcn_mfma_f32_16x16x32_bf16(Ax[1], Bi[0], a, 0, 0, 0);     \
    a = __builtin_amdgcn_mfma_f32_16x16x32_bf16(Ax[0], Bi[1], a, 0, 0, 0);     \
    a = __builtin_amdgcn_mfma_f32_16x16x32_bf16(Ax[0], Bi[0], a, 0, 0, 0);

// single tile (2 chains)
#define MM1(qq)                                                                \
    {                                                                          \
        short8 Af[3];                                                          \
        const char* ap = Apl + (qq)*16*ROWB + abase;                           \
        _Pragma("unroll")                                                      \
        for (int p = 0; p < 3; ++p) Af[p] = *(const short8*)(ap + p*APL);      \
        f32x4 x0 = acc[qq][0], x1 = acc[qq][1];                                \
        MFMA6(Af, Bf[0], x0)                                                   \
        MFMA6(Af, Bf[1], x1)                                                   \
        acc[qq][0] = x0; acc[qq][1] = x1;                                      \
    }

// pair of tiles (4 interleaved chains)
#define MM2(qa, qbb)                                                           \
    {                                                                          \
        short8 Aa[3], Ab[3];                                                   \
        const char* apa = Apl + (qa)*16*ROWB + abase;                          \
        const char* apb = Apl + (qbb)*16*ROWB + abase;                         \
        _Pragma("unroll")                                                      \
        for (int p = 0; p < 3; ++p) {                                          \
            Aa[p] = *(const short8*)(apa + p*APL);                             \
            Ab[p] = *(const short8*)(apb + p*APL);                             \
        }                                                                      \
        f32x4 x0 = acc[qa][0],  x1 = acc[qa][1];                               \
        f32x4 y0 = acc[qbb][0], y1 = acc[qbb][1];                              \
        x0 = __builtin_amdgcn_mfma_f32_16x16x32_bf16(Aa[2], Bf[0][0], x0, 0,0,0); \
        x1 = __builtin_amdgcn_mfma_f32_16x16x32_bf16(Aa[2], Bf[1][0], x1, 0,0,0); \
        y0 = __builtin_amdgcn_mfma_f32_16x16x32_bf16(Ab[2], Bf[0][0], y0, 0,0,0); \
        y1 = __builtin_amdgcn_mfma_f32_16x16x32_bf16(Ab[2], Bf[1][0], y1, 0,0,0); \
        x0 = __builtin_amdgcn_mfma_f32_16x16x32_bf16(Aa[1], Bf[0][1], x0, 0,0,0); \
        x1 = __builtin_amdgcn_mfma_f32_16x16x32_bf16(Aa[1], Bf[1][1], x1, 0,0,0); \
        y0 = __builtin_amdgcn_mfma_f32_16x16x32_bf16(Ab[1], Bf[0][1], y0, 0,0,0); \
        y1 = __builtin_amdgcn_mfma_f32_16x16x32_bf16(Ab[1], Bf[1][1], y1, 0,0,0); \
        x0 = __builtin_amdgcn_mfma_f32_16x16x32_bf16(Aa[0], Bf[0][2], x0, 0,0,0); \
        x1 = __builtin_amdgcn_mfma_f32_16x16x32_bf16(Aa[0], Bf[1][2], x1, 0,0,0); \
        y0 = __builtin_amdgcn_mfma_f32_16x16x32_bf16(Ab[0], Bf[0][2], y0, 0,0,0); \
        y1 = __builtin_amdgcn_mfma_f32_16x16x32_bf16(Ab[0], Bf[1][2], y1, 0,0,0); \
        x0 = __builtin_amdgcn_mfma_f32_16x16x32_bf16(Aa[1], Bf[0][0], x0, 0,0,0); \
        x1 = __builtin_amdgcn_mfma_f32_16x16x32_bf16(Aa[1], Bf[1][0], x1, 0,0,0); \
        y0 = __builtin_amdgcn_mfma_f32_16x16x32_bf16(Ab[1], Bf[0][0], y0, 0,0,0); \
        y1 = __builtin_amdgcn_mfma_f32_16x16x32_bf16(Ab[1], Bf[1][0], y1, 0,0,0); \
        x0 = __builtin_amdgcn_mfma_f32_16x16x32_bf16(Aa[0], Bf[0][1], x0, 0,0,0); \
        x1 = __builtin_amdgcn_mfma_f32_16x16x32_bf16(Aa[0], Bf[1][1], x1, 0,0,0); \
        y0 = __builtin_amdgcn_mfma_f32_16x16x32_bf16(Ab[0], Bf[0][1], y0, 0,0,0); \
        y1 = __builtin_amdgcn_mfma_f32_16x16x32_bf16(Ab[0], Bf[1][1], y1, 0,0,0); \
        x0 = __builtin_amdgcn_mfma_f32_16x16x32_bf16(Aa[0], Bf[0][0], x0, 0,0,0); \
        x1 = __builtin_amdgcn_mfma_f32_16x16x32_bf16(Aa[0], Bf[1][0], x1, 0,0,0); \
        y0 = __builtin_amdgcn_mfma_f32_16x16x32_bf16(Ab[0], Bf[0][0], y0, 0,0,0); \
        y1 = __builtin_amdgcn_mfma_f32_16x16x32_bf16(Ab[0], Bf[1][0], y1, 0,0,0); \
        acc[qa][0]  = x0; acc[qa][1]  = x1;                                    \
        acc[qbb][0] = y0; acc[qbb][1] = y1;                                    \
    }

// ---------------------------------------------------------------------------
// Encoder v11: R18/R19 structure + paired-tile MFMA (4 interleaved chains
// when a (2k,2k+1) pair lies fully inside one type section).
// ---------------------------------------------------------------------------
__global__ __launch_bounds__(256, 3) void k_enc(
    const int*   __restrict__ lists,
    const int*   __restrict__ counts,
    const float* __restrict__ PQ,
    const unsigned short* __restrict__ W2f,
    const float* __restrict__ b2,    // (2,256)
    float* __restrict__ node_msg)
{
    const int lb     = (blockIdx.x & 7)*192 + (blockIdx.x >> 3);  // XCD cluster
    const int b      = lb / 48;
    const int rem    = lb % 48;
    const int pair   = rem >> 1;
    const int nthalf = rem & 1;
    const int n0     = pair * 2;
    const int tid    = threadIdx.x;
    const int lane   = tid & 63, wave = tid >> 6;
    const unsigned PSEL = 0x07060302u;

    __shared__ __align__(16) char Apl[3*APL];   // 26.9 KB
    __shared__ int rowinfo_s[TMAX*16];

    const int c00 = counts[(b*NN + n0    )*2 + 0];
    const int c10 = counts[(b*NN + n0    )*2 + 1];
    const int c01 = counts[(b*NN + n0 + 1)*2 + 0];
    const int c11 = counts[(b*NN + n0 + 1)*2 + 1];
    const int tA  = c00 + c01, tB = c10 + c11;
    const int tAt = (tA + 15) >> 4, tBt = (tB + 15) >> 4;
    const int tiles = tAt + tBt;
    const int rows  = tiles*16;

    if (tid < TMAX*16) {
        const int r = tid;
        int g = 4, src = 0;
        if (r < tAt*16) {
            if (r < c00)     { src = lists[(b*NN + n0    )*LSTR + r];        g = 0; }
            else if (r < tA) { src = lists[(b*NN + n0 + 1)*LSTR + (r - c00)]; g = 1; }
        } else if (r < rows) {
            const int s = r - tAt*16;
            if (s < c10)     { src = lists[(b*NN + n0    )*LSTR + c00 + s];        g = 2; }
            else if (s < tB) { src = lists[(b*NN + n0 + 1)*LSTR + c01 + (s - c10)]; g = 3; }
        }
        rowinfo_s[r] = src | (g << 8);
    }
    __syncthreads();

    f32x4 acc[TMAX][2];
    #pragma unroll
    for (int q = 0; q < TMAX; ++q) {
        acc[q][0] = (f32x4){0.f, 0.f, 0.f, 0.f};
        acc[q][1] = (f32x4){0.f, 0.f, 0.f, 0.f};
    }

    const float* PQb = PQ + (size_t)b*NN*PQS;
    const int ntb  = nthalf*8 + wave*2;
    const int abase = (lane & 15)*ROWB + (lane >> 4)*16;

    #pragma unroll 1
    for (int kt = 0; kt < 8; ++kt) {
        // ---- cooperative A-build: 448 items over 256 threads ----
        #pragma unroll
        for (int pass = 0; pass < 2; ++pass) {
            const int item = tid + pass*256;
            const int row  = item >> 2, quad = item & 3;
            if (row < rows) {
                const int info = rowinfo_s[row];
                const int src  = info & 255;
                const int nd   = (info >> 8) & 1;
                const int tq   = (row >= tAt*16) ? 1 : 0;
                const int cols = kt*32 + quad*8;
                const float* pr = PQb + src*PQS      + tq*512 +       cols;
                const float* qr = PQb + (n0+nd)*PQS  + tq*512 + 256 + cols;
                const float4 Pa = *(const float4*)pr, Pb = *(const float4*)(pr+4);
                const float4 Qa = *(const float4*)qr, Qb = *(const float4*)(qr+4);
                const float u0 = fmaxf(Pa.x + Qa.x, 0.f);
                const float u1 = fmaxf(Pa.y + Qa.y, 0.f);
                const float u2 = fmaxf(Pa.z + Qa.z, 0.f);
                const float u3 = fmaxf(Pa.w + Qa.w, 0.f);
                const float u4 = fmaxf(Pb.x + Qb.x, 0.f);
                const float u5 = fmaxf(Pb.y + Qb.y, 0.f);
                const float u6 = fmaxf(Pb.z + Qb.z, 0.f);
                const float u7 = fmaxf(Pb.w + Qb.w, 0.f);
                const Split3 s0 = split2(u0, u1, PSEL);
                const Split3 s1 = split2(u2, u3, PSEL);
                const Split3 s2 = split2(u4, u5, PSEL);
                const Split3 s3 = split2(u6, u7, PSEL);
                char* w = Apl + row*ROWB + quad*16;
                PackA A0, A1, A2;
                A0.u[0]=s0.d0; A0.u[1]=s1.d0; A0.u[2]=s2.d0; A0.u[3]=s3.d0;
                A1.u[0]=s0.d1; A1.u[1]=s1.d1; A1.u[2]=s2.d1; A1.u[3]=s3.d1;
                A2.u[0]=s0.d2; A2.u[1]=s1.d2; A2.u[2]=s2.d2; A2.u[3]=s3.d2;
                *(short8*)(w)         = A0.s;
                *(short8*)(w + APL)   = A1.s;
                *(short8*)(w + 2*APL) = A2.s;
            }
        }
        __syncthreads();

        // ---- MFMA: paired tiles (4 chains) within sections ----
        #pragma unroll
        for (int sec = 0; sec < 2; ++sec) {
            const int qlo = sec ? tAt : 0;
            const int qhi = sec ? tiles : tAt;
            if (qlo >= qhi) continue;
            short8 Bf[2][3];
            #pragma unroll
            for (int i = 0; i < 2; ++i)
                #pragma unroll
                for (int p = 0; p < 3; ++p)
                    Bf[i][p] = *(const short8*)(W2f + ((size_t)(sec*3+p)*65536
                                 + (size_t)kt*8192 + (size_t)(ntb + i)*512 + (size_t)lane*8));
            #pragma unroll
            for (int k2 = 0; k2 < 3; ++k2) {
                const int qa = 2*k2, qbb = 2*k2 + 1;
                const bool ina = (qa >= qlo && qa < qhi);
                const bool inb = (qbb >= qlo && qbb < qhi);
                if (ina && inb) { MM2(qa, qbb) }
                else if (ina)   { MM1(qa) }
                else if (inb)   { MM1(qbb) }
            }
            if (6 >= qlo && 6 < qhi) { MM1(6) }
        }
        __syncthreads();
    }

    // ---- readout: relu(acc+b2), per-row node mask, shfl-reduce, store ----
    float b2v[2][2];
    #pragma unroll
    for (int t = 0; t < 2; ++t)
        #pragma unroll
        for (int i = 0; i < 2; ++i)
            b2v[t][i] = b2[t*HH + (ntb + i)*16 + (lane & 15)];

    float p0[2], p1[2];
    p0[0] = p0[1] = p1[0] = p1[1] = 0.f;
    #pragma unroll
    for (int q = 0; q < TMAX; ++q) {
        if (q < tiles) {
            const bool secB = (q >= tAt);
            int gv[4];
            #pragma unroll
            for (int rr = 0; rr < 4; ++rr)
                gv[rr] = rowinfo_s[q*16 + (lane >> 4)*4 + rr] >> 8;
            #pragma unroll
            for (int i = 0; i < 2; ++i) {
                const float bias = secB ? b2v[1][i] : b2v[0][i];
                #pragma unroll
                for (int rr = 0; rr < 4; ++rr) {
                    const float v = fmaxf(acc[q][i][rr] + bias, 0.f);
                    const bool valid = gv[rr] < 4;
                    p0[i] += (valid && !(gv[rr] & 1)) ? v : 0.f;
                    p1[i] += (valid &&  (gv[rr] & 1)) ? v : 0.f;
                }
            }
        }
    }
    #pragma unroll
    for (int i = 0; i < 2; ++i) {
        float v0 = p0[i], v1 = p1[i];
        v0 += __shfl_xor(v0, 16); v0 += __shfl_xor(v0, 32);
        v1 += __shfl_xor(v1, 16); v1 += __shfl_xor(v1, 32);
        if ((lane >> 4) == 0) {
            node_msg[((size_t)(b*NN + n0  ))*HH + (ntb + i)*16 + lane] = v0;
            node_msg[((size_t)(b*NN + n0+1))*HH + (ntb + i)*16 + lane] = v1;
        }
    }
}

// ---------------------------------------------------------------------------
// Decoder: 2 rows/block (768 blocks — was 1.5 blocks/CU, latency-bound),
// XCD-clustered, fused next-step PQ production.
// ---------------------------------------------------------------------------
__global__ __launch_bounds__(256, 4) void k_dec(
    float* __restrict__ state,
    const float* __restrict__ nm,
    const float* __restrict__ W1, const float* __restrict__ b1,   // (272,256)
    const float* __restrict__ W2, const float* __restrict__ b2,   // (256,256)
    const float* __restrict__ W3, const float* __restrict__ b3,   // (256,16)
    const float* __restrict__ eW1T,  // (2,256,32)
    const float* __restrict__ eb1,   // (2,256)
    float* __restrict__ PQ,
    float* __restrict__ out, int step)
{
    const int lb   = (blockIdx.x & 7)*96 + (blockIdx.x >> 3);
    const int b    = lb / 24;
    const int row0 = (lb % 24) * 2;
    const int c    = threadIdx.x;

    __shared__ float in_s[2][272];
    __shared__ float d1s[2][HH];
    __shared__ float stn[2][DD];

    for (int i = c; i < 2*272; i += 256) {
        const int m = i / 272, k = i % 272;
        const int r = row0 + m;
        in_s[m][k] = (k < DD)
            ? state[((size_t)b*NN + r)*DD + k]
            : nm[((size_t)b*NN + r)*HH + (k - DD)];
    }
    __syncthreads();

    float a0[2];
    {
        const float bb = b1[c];
        a0[0] = bb; a0[1] = bb;
        #pragma unroll 2
        for (int k4 = 0; k4 < 68; ++k4) {
            const float* wr = W1 + (k4*4)*HH;
            const float w0=wr[c], w1_=wr[HH+c], w2_=wr[2*HH+c], w3=wr[3*HH+c];
            #pragma unroll
            for (int m = 0; m < 2; ++m) {
                const float4 h = *(const float4*)&in_s[m][k4*4];
                a0[m] = fmaf(h.x,w0, fmaf(h.y,w1_, fmaf(h.z,w2_, fmaf(h.w,w3, a0[m]))));
            }
        }
        #pragma unroll
        for (int m = 0; m < 2; ++m) d1s[m][c] = fmaxf(a0[m], 0.f);
    }
    __syncthreads();
    {
        const float bb = b2[c];
        a0[0] = bb; a0[1] = bb;
        #pragma unroll 2
        for (int k4 = 0; k4 < 64; ++k4) {
            const float* wr = W2 + (k4*4)*HH;
            const float w0=wr[c], w1_=wr[HH+c], w2_=wr[2*HH+c], w3=wr[3*HH+c];
            #pragma unroll
            for (int m = 0; m < 2; ++m) {
                const float4 h = *(const float4*)&d1s[m][k4*4];
                a0[m] = fmaf(h.x,w0, fmaf(h.y,w1_, fmaf(h.z,w2_, fmaf(h.w,w3, a0[m]))));
            }
        }
        __syncthreads();
        #pragma unroll
        for (int m = 0; m < 2; ++m) in_s[m][c] = fmaxf(a0[m], 0.f);
    }
    __syncthreads();
    if (c < 32) {
        const int m = c >> 4, cc = c & 15;
        float a = b3[cc];
        #pragma unroll 4
        for (int k4 = 0; k4 < 64; ++k4) {
            const float4 h = *(const float4*)&in_s[m][k4*4];
            a += h.x*W3[(k4*4+0)*16+cc] + h.y*W3[(k4*4+1)*16+cc]
               + h.z*W3[(k4*4+2)*16+cc] + h.w*W3[(k4*4+3)*16+cc];
        }
        const int r = row0 + m;
        const float v = state[((size_t)b*NN + r)*DD + cc] + a;
        state[((size_t)b*NN + r)*DD + cc] = v;
        out[(((size_t)b*NPRED + step)*NN + r)*DD + cc] = v;
        stn[m][cc] = v;
    }
    __syncthreads();
    float4 sm[2][4];
    #pragma unroll
    for (int m = 0; m < 2; ++m)
        #pragma unroll
        for (int f4 = 0; f4 < 4; ++f4)
            sm[m][f4] = *(const float4*)&stn[m][f4*4];
    #pragma unroll
    for (int k = 0; k < 4; ++k) {
        const int combo = c + 256*k;
        const int cc = combo & 255;
        const int pq = (combo >> 8) & 1;
        const int t  = combo >> 9;
        const float* wc = eW1T + ((size_t)t*HH + cc)*32 + pq*16;
        float4 w[4];
        #pragma unroll
        for (int f4 = 0; f4 < 4; ++f4) w[f4] = ((const float4*)wc)[f4];
        const float bias = pq ? eb1[t*HH + cc] : 0.f;
        #pragma unroll
        for (int m = 0; m < 2; ++m) {
            float v = bias;
            #pragma unroll
            for (int f4 = 0; f4 < 4; ++f4) {
                const float4 s = sm[m][f4];
                v = fmaf(s.x,w[f4].x, fmaf(s.y,w[f4].y, fmaf(s.z,w[f4].z, fmaf(s.w,w[f4].w, v))));
            }
            PQ[(size_t)(b*NN + row0 + m)*PQS + t*512 + pq*256 + cc] = v;
        }
    }
}

// ---------------------------------------------------------------------------
extern "C" void kernel_launch(void* const* d_in, const int* in_sizes, int n_in,
                              void* d_out, int out_size, void* d_ws, size_t ws_size,
                              hipStream_t stream)
{
    const float* time_segs  = (const float*)d_in[0];
    const float* edge_types = (const float*)d_in[1];
    const float* enc_W1 = (const float*)d_in[4];
    const float* enc_b1 = (const float*)d_in[5];
    const float* enc_W2 = (const float*)d_in[6];
    const float* enc_b2 = (const float*)d_in[7];
    const float* dec_W1 = (const float*)d_in[8];
    const float* dec_b1 = (const float*)d_in[9];
    const float* dec_W2 = (const float*)d_in[10];
    const float* dec_b2 = (const float*)d_in[11];
    const float* out_W  = (const float*)d_in[12];
    const float* out_b  = (const float*)d_in[13];
    float* out = (float*)d_out;

    // workspace (~9.3 MB)
    float* state    = (float*)d_ws;                    // 24576 f
    float* node_msg = state + BB*NN*DD;                // 393216 f
    float* W1T      = node_msg + BB*NN*HH;             // 16384 f
    unsigned short* W2f = (unsigned short*)(W1T + 2*HH*32);   // 393216 us
    int*   lists    = (int*)(W2f + 2*3*65536);         // 86016 i
    int*   counts   = lists + BB*NN*LSTR;              // 3072 i
    float* PQ       = (float*)(counts + BB*NN*2);      // 1597440 f

    k_setup<<<384, 256, 0, stream>>>(time_segs, edge_types, enc_W1, enc_W2,
                                     enc_b1, state, W1T, W2f, PQ, lists, counts);
    for (int stp = 0; stp < NPRED; ++stp) {
        k_enc<<<BB*NN, 256, 0, stream>>>(lists, counts, PQ, W2f,
                                         enc_b2, node_msg);
        k_dec<<<BB*24, 256, 0, stream>>>(state, node_msg,
                                         dec_W1, dec_b1, dec_W2, dec_b2,
                                         out_W, out_b, W1T, enc_b1, PQ, out, stp);
    }
}

// Round 22
// 594.485 us; speedup vs baseline: 1.2330x; 1.0349x over previous
//
#include <hip/hip_runtime.h>

#define NN    48
#define DD    16
#define HH    256
#define EE    2256
#define BB    32
#define NPRED 8
#define LSTR  56
#define PQS   1040                   // PQ per-node stride (floats), de-pow2
#define TMAX  7                      // packed tiles/pair <= 7 (tA+tB<=94)
#define ROWB  80                     // A-plane row stride bytes (5x16B, 2-way banks)
#define APL   (TMAX*16*ROWB)         // 8960 B per plane

typedef __attribute__((ext_vector_type(4))) float f32x4;
typedef __attribute__((ext_vector_type(8))) short short8;

__device__ __forceinline__ float bf2f(unsigned short h) {
    union { unsigned u; float f; } v; v.u = ((unsigned)h) << 16; return v.f;
}
__device__ __forceinline__ unsigned short f2bf(float x) {
    union { float f; unsigned u; } v; v.f = x;
    unsigned r = v.u + 0x7fffu + ((v.u >> 16) & 1u);
    return (unsigned short)(r >> 16);
}
__device__ __forceinline__ unsigned perm_hi16(unsigned xB, unsigned xA, unsigned sel) {
    unsigned d;
    asm("v_perm_b32 %0, %1, %2, %3" : "=v"(d) : "v"(xB), "v"(xA), "s"(sel));
    return d;
}
struct Split3 { unsigned d0, d1, d2; };
__device__ __forceinline__ Split3 split2(float u0, float u1, unsigned sel)
{
    union F { float f; unsigned u; };
    Split3 o;
    F x0, x1; x0.f = u0; x1.f = u1;
    o.d0 = perm_hi16(x1.u, x0.u, sel);
    F h0a, h0b; h0a.u = x0.u & 0xffff0000u; h0b.u = x1.u & 0xffff0000u;
    F e0a, e0b; e0a.f = u0 - h0a.f; e0b.f = u1 - h0b.f;
    o.d1 = perm_hi16(e0b.u, e0a.u, sel);
    F h1a, h1b; h1a.u = e0a.u & 0xffff0000u; h1b.u = e0b.u & 0xffff0000u;
    F e1a, e1b; e1a.f = e0a.f - h1a.f; e1b.f = e0b.f - h1b.f;
    o.d2 = perm_hi16(e1b.u, e1a.u, sel);
    return o;
}
union PackA { unsigned u[4]; short8 s; };

// ---------------------------------------------------------------------------
// Setup (384 blocks) — unchanged (verified).
// ---------------------------------------------------------------------------
__global__ __launch_bounds__(256) void k_setup(
    const float* __restrict__ time_segs,
    const float* __restrict__ edge_types,
    const float* __restrict__ W1,      // (2,32,256)
    const float* __restrict__ W2,      // (2,256,256)
    const float* __restrict__ b1,      // (2,256)
    float* __restrict__ state,
    float* __restrict__ W1T,           // (2,256,32)
    unsigned short* __restrict__ W2f,  // 393216
    float* __restrict__ PQ,
    int* __restrict__ lists,
    int* __restrict__ counts)
{
    const int tid = blockIdx.x * 256 + threadIdx.x;
    const int NT = 384*256;
    for (int i = tid; i < BB*NN*DD; i += NT)
        state[i] = time_segs[i];
    for (int i = tid; i < 2*HH*32; i += NT) {
        const int t = i >> 13, r = i & 8191, h = r >> 5, f = r & 31;
        W1T[i] = W1[(t*32 + f)*HH + h];
    }
    for (int i = tid; i < 2*8*16*64*8; i += NT) {
        const int j  = i & 7, l = (i >> 3) & 63, nt = (i >> 9) & 15;
        const int kt = (i >> 13) & 7, t = (i >> 16) & 1;
        const int k = kt*32 + ((l >> 4) << 3) + j;
        const int n = nt*16 + (l & 15);
        const float w = W2[((size_t)t*HH + k)*HH + n];
        const unsigned short h0 = f2bf(w);  const float r1 = w  - bf2f(h0);
        const unsigned short h1 = f2bf(r1); const float r2 = r1 - bf2f(h1);
        const unsigned short h2 = f2bf(r2);
        const size_t rest = (size_t)kt*8192 + nt*512 + l*8 + j;
        W2f[(size_t)(t*3+0)*65536 + rest] = h0;
        W2f[(size_t)(t*3+1)*65536 + rest] = h1;
        W2f[(size_t)(t*3+2)*65536 + rest] = h2;
    }
    for (int i = tid; i < BB*NN*1024; i += NT) {
        const int c  = i & 255;
        const int pq = (i >> 8) & 1;
        const int t  = (i >> 9) & 1;
        const int nb = i >> 10;
        float v = pq ? b1[t*HH + c] : 0.f;
        #pragma unroll
        for (int f = 0; f < DD; ++f)
            v = fmaf(time_segs[nb*DD + f], W1[(t*32 + pq*16 + f)*HH + c], v);
        PQ[(size_t)nb*PQS + (i & 1023)] = v;
    }
    if (tid < BB*NN) {
        const int b = tid / NN;
        const int n = tid % NN;
        int* lst = lists + tid * LSTR;
        int c = 0;
        for (int s = 0; s < NN; ++s) {
            if (s == n) continue;
            const int e = s * 47 + (n > s ? n - 1 : n);
            if (edge_types[((size_t)b*EE + e)*3 + 1] > 0.5f) lst[c++] = s;
        }
        const int c1 = c;
        for (int s = 0; s < NN; ++s) {
            if (s == n) continue;
            const int e = s * 47 + (n > s ? n - 1 : n);
            if (edge_types[((size_t)b*EE + e)*3 + 2] > 0.5f) lst[c++] = s;
        }
        counts[tid*2 + 0] = c1;
        counts[tid*2 + 1] = c - c1;
        for (int i = c; i < LSTR; ++i) lst[i] = 0;
    }
}

#define MFMA6(Ax, Bi, a)                                                       \
    a = __builtin_amdgcn_mfma_f32_16x16x32_bf16(Ax[2], Bi[0], a, 0, 0, 0);     \
    a = __builtin_amdgcn_mfma_f32_16x16x32_bf16(Ax[1], Bi[1], a, 0, 0, 0);     \
    a = __builtin_amdgcn_mfma_f32_16x16x32_bf16(Ax[0], Bi[2], a, 0, 0, 0);     \
    a = __builtin_amdgcn_mfma_f32_16x16x32_bf16(Ax[1], Bi[0], a, 0, 0, 0);     \
    a = __builtin_amdgcn_mfma_f32_16x16x32_bf16(Ax[0], Bi[1], a, 0, 0, 0);     \
    a = __builtin_amdgcn_mfma_f32_16x16x32_bf16(Ax[0], Bi[0], a, 0, 0, 0);

#define MM1(qq)                                                                \
    {                                                                          \
        short8 Af[3];                                                          \
        const char* ap = Apl + (qq)*16*ROWB + abase;                           \
        _Pragma("unroll")                                                      \
        for (int p = 0; p < 3; ++p) Af[p] = *(const short8*)(ap + p*APL);      \
        f32x4 x0 = acc[qq][0], x1 = acc[qq][1];                                \
        MFMA6(Af, Bf[0], x0)                                                   \
        MFMA6(Af, Bf[1], x1)                                                   \
        acc[qq][0] = x0; acc[qq][1] = x1;                                      \
    }

// ---------------------------------------------------------------------------
// Encoder v12b: one block per pair (512 thr, 8 waves x 2 nt) — A-build done
// exactly ONCE per pair. R21 bug fixed: bijective XCD swizzle for 768
// blocks is (bid&7)*96 + (bid>>3)  [was *48 -> collisions, half missing].
// ---------------------------------------------------------------------------
__global__ __launch_bounds__(512, 4) void k_enc(
    const int*   __restrict__ lists,
    const int*   __restrict__ counts,
    const float* __restrict__ PQ,
    const unsigned short* __restrict__ W2f,
    const float* __restrict__ b2,    // (2,256)
    float* __restrict__ node_msg)
{
    const int lb   = (blockIdx.x & 7)*96 + (blockIdx.x >> 3);  // 768 = 8*96
    const int b    = lb / 24;            // 4 batches per XCD
    const int pair = lb % 24;
    const int n0   = pair * 2;
    const int tid  = threadIdx.x;        // 0..511
    const int lane = tid & 63, wave = tid >> 6;   // 8 waves
    const unsigned PSEL = 0x07060302u;

    __shared__ __align__(16) char Apl[3*APL];   // 26.9 KB
    __shared__ int rowinfo_s[TMAX*16];

    const int c00 = counts[(b*NN + n0    )*2 + 0];
    const int c10 = counts[(b*NN + n0    )*2 + 1];
    const int c01 = counts[(b*NN + n0 + 1)*2 + 0];
    const int c11 = counts[(b*NN + n0 + 1)*2 + 1];
    const int tA  = c00 + c01, tB = c10 + c11;
    const int tAt = (tA + 15) >> 4, tBt = (tB + 15) >> 4;
    const int tiles = tAt + tBt;
    const int rows  = tiles*16;

    if (tid < TMAX*16) {
        const int r = tid;
        int g = 4, src = 0;
        if (r < tAt*16) {
            if (r < c00)     { src = lists[(b*NN + n0    )*LSTR + r];        g = 0; }
            else if (r < tA) { src = lists[(b*NN + n0 + 1)*LSTR + (r - c00)]; g = 1; }
        } else if (r < rows) {
            const int s = r - tAt*16;
            if (s < c10)     { src = lists[(b*NN + n0    )*LSTR + c00 + s];        g = 2; }
            else if (s < tB) { src = lists[(b*NN + n0 + 1)*LSTR + c01 + (s - c10)]; g = 3; }
        }
        rowinfo_s[r] = src | (g << 8);
    }
    __syncthreads();

    f32x4 acc[TMAX][2];
    #pragma unroll
    for (int q = 0; q < TMAX; ++q) {
        acc[q][0] = (f32x4){0.f, 0.f, 0.f, 0.f};
        acc[q][1] = (f32x4){0.f, 0.f, 0.f, 0.f};
    }

    const float* PQb = PQ + (size_t)b*NN*PQS;
    const int ntb  = wave*2;             // this wave's first n-tile (0..14)
    const int abase = (lane & 15)*ROWB + (lane >> 4)*16;

    #pragma unroll 1
    for (int kt = 0; kt < 8; ++kt) {
        // ---- cooperative A-build: <=448 items over 512 threads (1 pass) ----
        {
            const int row  = tid >> 2, quad = tid & 3;
            if (row < rows) {
                const int info = rowinfo_s[row];
                const int src  = info & 255;
                const int nd   = (info >> 8) & 1;
                const int tq   = (row >= tAt*16) ? 1 : 0;
                const int cols = kt*32 + quad*8;
                const float* pr = PQb + src*PQS      + tq*512 +       cols;
                const float* qr = PQb + (n0+nd)*PQS  + tq*512 + 256 + cols;
                const float4 Pa = *(const float4*)pr, Pb = *(const float4*)(pr+4);
                const float4 Qa = *(const float4*)qr, Qb = *(const float4*)(qr+4);
                const float u0 = fmaxf(Pa.x + Qa.x, 0.f);
                const float u1 = fmaxf(Pa.y + Qa.y, 0.f);
                const float u2 = fmaxf(Pa.z + Qa.z, 0.f);
                const float u3 = fmaxf(Pa.w + Qa.w, 0.f);
                const float u4 = fmaxf(Pb.x + Qb.x, 0.f);
                const float u5 = fmaxf(Pb.y + Qb.y, 0.f);
                const float u6 = fmaxf(Pb.z + Qb.z, 0.f);
                const float u7 = fmaxf(Pb.w + Qb.w, 0.f);
                const Split3 s0 = split2(u0, u1, PSEL);
                const Split3 s1 = split2(u2, u3, PSEL);
                const Split3 s2 = split2(u4, u5, PSEL);
                const Split3 s3 = split2(u6, u7, PSEL);
                char* w = Apl + row*ROWB + quad*16;
                PackA A0, A1, A2;
                A0.u[0]=s0.d0; A0.u[1]=s1.d0; A0.u[2]=s2.d0; A0.u[3]=s3.d0;
                A1.u[0]=s0.d1; A1.u[1]=s1.d1; A1.u[2]=s2.d1; A1.u[3]=s3.d1;
                A2.u[0]=s0.d2; A2.u[1]=s1.d2; A2.u[2]=s2.d2; A2.u[3]=s3.d2;
                *(short8*)(w)         = A0.s;
                *(short8*)(w + APL)   = A1.s;
                *(short8*)(w + 2*APL) = A2.s;
            }
        }
        __syncthreads();

        // ---- MFMA: all tiles x this wave's 2 n-tiles, A from LDS ----
        #pragma unroll
        for (int sec = 0; sec < 2; ++sec) {
            const int qlo = sec ? tAt : 0;
            const int qhi = sec ? tiles : tAt;
            if (qlo >= qhi) continue;
            short8 Bf[2][3];
            #pragma unroll
            for (int i = 0; i < 2; ++i)
                #pragma unroll
                for (int p = 0; p < 3; ++p)
                    Bf[i][p] = *(const short8*)(W2f + ((size_t)(sec*3+p)*65536
                                 + (size_t)kt*8192 + (size_t)(ntb + i)*512 + (size_t)lane*8));
            #pragma unroll
            for (int q = 0; q < TMAX; ++q) {
                if (q >= qlo && q < qhi) { MM1(q) }
            }
        }
        __syncthreads();
    }

    // ---- readout: relu(acc+b2), per-row node mask, shfl-reduce, store ----
    float b2v[2][2];
    #pragma unroll
    for (int t = 0; t < 2; ++t)
        #pragma unroll
        for (int i = 0; i < 2; ++i)
            b2v[t][i] = b2[t*HH + (ntb + i)*16 + (lane & 15)];

    float p0[2], p1[2];
    p0[0] = p0[1] = p1[0] = p1[1] = 0.f;
    #pragma unroll
    for (int q = 0; q < TMAX; ++q) {
        if (q < tiles) {
            const bool secB = (q >= tAt);
            int gv[4];
            #pragma unroll
            for (int rr = 0; rr < 4; ++rr)
                gv[rr] = rowinfo_s[q*16 + (lane >> 4)*4 + rr] >> 8;
            #pragma unroll
            for (int i = 0; i < 2; ++i) {
                const float bias = secB ? b2v[1][i] : b2v[0][i];
                #pragma unroll
                for (int rr = 0; rr < 4; ++rr) {
                    const float v = fmaxf(acc[q][i][rr] + bias, 0.f);
                    const bool valid = gv[rr] < 4;
                    p0[i] += (valid && !(gv[rr] & 1)) ? v : 0.f;
                    p1[i] += (valid &&  (gv[rr] & 1)) ? v : 0.f;
                }
            }
        }
    }
    #pragma unroll
    for (int i = 0; i < 2; ++i) {
        float v0 = p0[i], v1 = p1[i];
        v0 += __shfl_xor(v0, 16); v0 += __shfl_xor(v0, 32);
        v1 += __shfl_xor(v1, 16); v1 += __shfl_xor(v1, 32);
        if ((lane >> 4) == 0) {
            node_msg[((size_t)(b*NN + n0  ))*HH + (ntb + i)*16 + lane] = v0;
            node_msg[((size_t)(b*NN + n0+1))*HH + (ntb + i)*16 + lane] = v1;
        }
    }
}

// ---------------------------------------------------------------------------
// Decoder: 6 rows/block (256 blocks = exactly 1/CU, 32/XCD), weights
// streamed once per block (138 MB/step), 6 ILP chains. Fused PQ production.
// ---------------------------------------------------------------------------
__global__ __launch_bounds__(256, 2) void k_dec(
    float* __restrict__ state,
    const float* __restrict__ nm,
    const float* __restrict__ W1, const float* __restrict__ b1,   // (272,256)
    const float* __restrict__ W2, const float* __restrict__ b2,   // (256,256)
    const float* __restrict__ W3, const float* __restrict__ b3,   // (256,16)
    const float* __restrict__ eW1T,  // (2,256,32)
    const float* __restrict__ eb1,   // (2,256)
    float* __restrict__ PQ,
    float* __restrict__ out, int step)
{
    const int lb   = (blockIdx.x & 7)*32 + (blockIdx.x >> 3);
    const int b    = lb / 8;
    const int row0 = (lb % 8) * 6;
    const int c    = threadIdx.x;

    __shared__ float in_s[6][272];
    __shared__ float d1s[6][HH];
    __shared__ float stn[6][DD];

    for (int i = c; i < 6*272; i += 256) {
        const int m = i / 272, k = i % 272;
        const int r = row0 + m;
        in_s[m][k] = (k < DD)
            ? state[((size_t)b*NN + r)*DD + k]
            : nm[((size_t)b*NN + r)*HH + (k - DD)];
    }
    __syncthreads();

    float a0[6];
    {
        const float bb = b1[c];
        #pragma unroll
        for (int m = 0; m < 6; ++m) a0[m] = bb;
        #pragma unroll 2
        for (int k4 = 0; k4 < 68; ++k4) {
            const float* wr = W1 + (k4*4)*HH;
            const float w0=wr[c], w1_=wr[HH+c], w2_=wr[2*HH+c], w3=wr[3*HH+c];
            #pragma unroll
            for (int m = 0; m < 6; ++m) {
                const float4 h = *(const float4*)&in_s[m][k4*4];
                a0[m] = fmaf(h.x,w0, fmaf(h.y,w1_, fmaf(h.z,w2_, fmaf(h.w,w3, a0[m]))));
            }
        }
        #pragma unroll
        for (int m = 0; m < 6; ++m) d1s[m][c] = fmaxf(a0[m], 0.f);
    }
    __syncthreads();
    {
        const float bb = b2[c];
        #pragma unroll
        for (int m = 0; m < 6; ++m) a0[m] = bb;
        #pragma unroll 2
        for (int k4 = 0; k4 < 64; ++k4) {
            const float* wr = W2 + (k4*4)*HH;
            const float w0=wr[c], w1_=wr[HH+c], w2_=wr[2*HH+c], w3=wr[3*HH+c];
            #pragma unroll
            for (int m = 0; m < 6; ++m) {
                const float4 h = *(const float4*)&d1s[m][k4*4];
                a0[m] = fmaf(h.x,w0, fmaf(h.y,w1_, fmaf(h.z,w2_, fmaf(h.w,w3, a0[m]))));
            }
        }
        __syncthreads();
        #pragma unroll
        for (int m = 0; m < 6; ++m) in_s[m][c] = fmaxf(a0[m], 0.f);
    }
    __syncthreads();
    if (c < 96) {
        const int m = c >> 4, cc = c & 15;
        float a = b3[cc];
        #pragma unroll 4
        for (int k4 = 0; k4 < 64; ++k4) {
            const float4 h = *(const float4*)&in_s[m][k4*4];
            a += h.x*W3[(k4*4+0)*16+cc] + h.y*W3[(k4*4+1)*16+cc]
               + h.z*W3[(k4*4+2)*16+cc] + h.w*W3[(k4*4+3)*16+cc];
        }
        const int r = row0 + m;
        const float v = state[((size_t)b*NN + r)*DD + cc] + a;
        state[((size_t)b*NN + r)*DD + cc] = v;
        out[(((size_t)b*NPRED + step)*NN + r)*DD + cc] = v;
        stn[m][cc] = v;
    }
    __syncthreads();
    float4 sm[6][4];
    #pragma unroll
    for (int m = 0; m < 6; ++m)
        #pragma unroll
        for (int f4 = 0; f4 < 4; ++f4)
            sm[m][f4] = *(const float4*)&stn[m][f4*4];
    #pragma unroll
    for (int k = 0; k < 4; ++k) {
        const int combo = c + 256*k;
        const int cc = combo & 255;
        const int pq = (combo >> 8) & 1;
        const int t  = combo >> 9;
        const float* wc = eW1T + ((size_t)t*HH + cc)*32 + pq*16;
        float4 w[4];
        #pragma unroll
        for (int f4 = 0; f4 < 4; ++f4) w[f4] = ((const float4*)wc)[f4];
        const float bias = pq ? eb1[t*HH + cc] : 0.f;
        #pragma unroll
        for (int m = 0; m < 6; ++m) {
            float v = bias;
            #pragma unroll
            for (int f4 = 0; f4 < 4; ++f4) {
                const float4 s = sm[m][f4];
                v = fmaf(s.x,w[f4].x, fmaf(s.y,w[f4].y, fmaf(s.z,w[f4].z, fmaf(s.w,w[f4].w, v))));
            }
            PQ[(size_t)(b*NN + row0 + m)*PQS + t*512 + pq*256 + cc] = v;
        }
    }
}

// ---------------------------------------------------------------------------
extern "C" void kernel_launch(void* const* d_in, const int* in_sizes, int n_in,
                              void* d_out, int out_size, void* d_ws, size_t ws_size,
                              hipStream_t stream)
{
    const float* time_segs  = (const float*)d_in[0];
    const float* edge_types = (const float*)d_in[1];
    const float* enc_W1 = (const float*)d_in[4];
    const float* enc_b1 = (const float*)d_in[5];
    const float* enc_W2 = (const float*)d_in[6];
    const float* enc_b2 = (const float*)d_in[7];
    const float* dec_W1 = (const float*)d_in[8];
    const float* dec_b1 = (const float*)d_in[9];
    const float* dec_W2 = (const float*)d_in[10];
    const float* dec_b2 = (const float*)d_in[11];
    const float* out_W  = (const float*)d_in[12];
    const float* out_b  = (const float*)d_in[13];
    float* out = (float*)d_out;

    // workspace (~9.3 MB)
    float* state    = (float*)d_ws;                    // 24576 f
    float* node_msg = state + BB*NN*DD;                // 393216 f
    float* W1T      = node_msg + BB*NN*HH;             // 16384 f
    unsigned short* W2f = (unsigned short*)(W1T + 2*HH*32);   // 393216 us
    int*   lists    = (int*)(W2f + 2*3*65536);         // 86016 i
    int*   counts   = lists + BB*NN*LSTR;              // 3072 i
    float* PQ       = (float*)(counts + BB*NN*2);      // 1597440 f

    k_setup<<<384, 256, 0, stream>>>(time_segs, edge_types, enc_W1, enc_W2,
                                     enc_b1, state, W1T, W2f, PQ, lists, counts);
    for (int stp = 0; stp < NPRED; ++stp) {
        k_enc<<<BB*24, 512, 0, stream>>>(lists, counts, PQ, W2f,
                                         enc_b2, node_msg);
        k_dec<<<BB*8, 256, 0, stream>>>(state, node_msg,
                                        dec_W1, dec_b1, dec_W2, dec_b2,
                                        out_W, out_b, W1T, enc_b1, PQ, out, stp);
    }
}

// Round 23
// 571.440 us; speedup vs baseline: 1.2827x; 1.0403x over previous
//
#include <hip/hip_runtime.h>

#define NN    48
#define DD    16
#define HH    256
#define EE    2256
#define BB    32
#define NPRED 8
#define LSTR  56
#define PQS   1040                   // PQ per-node stride (floats), de-pow2
#define TMAX  7                      // packed tiles/pair <= 7 (tA+tB<=94)
#define ROWB  80                     // A-plane row stride bytes (5x16B, 2-way banks)
#define APL   (TMAX*16*ROWB)         // 8960 B per plane
#define ABUF  (3*APL)                // one dbuf half (3 planes) = 26880 B

typedef __attribute__((ext_vector_type(4))) float f32x4;
typedef __attribute__((ext_vector_type(8))) short short8;

__device__ __forceinline__ float bf2f(unsigned short h) {
    union { unsigned u; float f; } v; v.u = ((unsigned)h) << 16; return v.f;
}
__device__ __forceinline__ unsigned short f2bf(float x) {
    union { float f; unsigned u; } v; v.f = x;
    unsigned r = v.u + 0x7fffu + ((v.u >> 16) & 1u);
    return (unsigned short)(r >> 16);
}
__device__ __forceinline__ unsigned perm_hi16(unsigned xB, unsigned xA, unsigned sel) {
    unsigned d;
    asm("v_perm_b32 %0, %1, %2, %3" : "=v"(d) : "v"(xB), "v"(xA), "s"(sel));
    return d;
}
struct Split3 { unsigned d0, d1, d2; };
__device__ __forceinline__ Split3 split2(float u0, float u1, unsigned sel)
{
    union F { float f; unsigned u; };
    Split3 o;
    F x0, x1; x0.f = u0; x1.f = u1;
    o.d0 = perm_hi16(x1.u, x0.u, sel);
    F h0a, h0b; h0a.u = x0.u & 0xffff0000u; h0b.u = x1.u & 0xffff0000u;
    F e0a, e0b; e0a.f = u0 - h0a.f; e0b.f = u1 - h0b.f;
    o.d1 = perm_hi16(e0b.u, e0a.u, sel);
    F h1a, h1b; h1a.u = e0a.u & 0xffff0000u; h1b.u = e0b.u & 0xffff0000u;
    F e1a, e1b; e1a.f = e0a.f - h1a.f; e1b.f = e0b.f - h1b.f;
    o.d2 = perm_hi16(e1b.u, e1a.u, sel);
    return o;
}
union PackA { unsigned u[4]; short8 s; };

// ---------------------------------------------------------------------------
// Setup (384 blocks) — unchanged (verified).
// ---------------------------------------------------------------------------
__global__ __launch_bounds__(256) void k_setup(
    const float* __restrict__ time_segs,
    const float* __restrict__ edge_types,
    const float* __restrict__ W1,      // (2,32,256)
    const float* __restrict__ W2,      // (2,256,256)
    const float* __restrict__ b1,      // (2,256)
    float* __restrict__ state,
    float* __restrict__ W1T,           // (2,256,32)
    unsigned short* __restrict__ W2f,  // 393216
    float* __restrict__ PQ,
    int* __restrict__ lists,
    int* __restrict__ counts)
{
    const int tid = blockIdx.x * 256 + threadIdx.x;
    const int NT = 384*256;
    for (int i = tid; i < BB*NN*DD; i += NT)
        state[i] = time_segs[i];
    for (int i = tid; i < 2*HH*32; i += NT) {
        const int t = i >> 13, r = i & 8191, h = r >> 5, f = r & 31;
        W1T[i] = W1[(t*32 + f)*HH + h];
    }
    for (int i = tid; i < 2*8*16*64*8; i += NT) {
        const int j  = i & 7, l = (i >> 3) & 63, nt = (i >> 9) & 15;
        const int kt = (i >> 13) & 7, t = (i >> 16) & 1;
        const int k = kt*32 + ((l >> 4) << 3) + j;
        const int n = nt*16 + (l & 15);
        const float w = W2[((size_t)t*HH + k)*HH + n];
        const unsigned short h0 = f2bf(w);  const float r1 = w  - bf2f(h0);
        const unsigned short h1 = f2bf(r1); const float r2 = r1 - bf2f(h1);
        const unsigned short h2 = f2bf(r2);
        const size_t rest = (size_t)kt*8192 + nt*512 + l*8 + j;
        W2f[(size_t)(t*3+0)*65536 + rest] = h0;
        W2f[(size_t)(t*3+1)*65536 + rest] = h1;
        W2f[(size_t)(t*3+2)*65536 + rest] = h2;
    }
    for (int i = tid; i < BB*NN*1024; i += NT) {
        const int c  = i & 255;
        const int pq = (i >> 8) & 1;
        const int t  = (i >> 9) & 1;
        const int nb = i >> 10;
        float v = pq ? b1[t*HH + c] : 0.f;
        #pragma unroll
        for (int f = 0; f < DD; ++f)
            v = fmaf(time_segs[nb*DD + f], W1[(t*32 + pq*16 + f)*HH + c], v);
        PQ[(size_t)nb*PQS + (i & 1023)] = v;
    }
    if (tid < BB*NN) {
        const int b = tid / NN;
        const int n = tid % NN;
        int* lst = lists + tid * LSTR;
        int c = 0;
        for (int s = 0; s < NN; ++s) {
            if (s == n) continue;
            const int e = s * 47 + (n > s ? n - 1 : n);
            if (edge_types[((size_t)b*EE + e)*3 + 1] > 0.5f) lst[c++] = s;
        }
        const int c1 = c;
        for (int s = 0; s < NN; ++s) {
            if (s == n) continue;
            const int e = s * 47 + (n > s ? n - 1 : n);
            if (edge_types[((size_t)b*EE + e)*3 + 2] > 0.5f) lst[c++] = s;
        }
        counts[tid*2 + 0] = c1;
        counts[tid*2 + 1] = c - c1;
        for (int i = c; i < LSTR; ++i) lst[i] = 0;
    }
}

#define MFMA6(Ax, Bi, a)                                                       \
    a = __builtin_amdgcn_mfma_f32_16x16x32_bf16(Ax[2], Bi[0], a, 0, 0, 0);     \
    a = __builtin_amdgcn_mfma_f32_16x16x32_bf16(Ax[1], Bi[1], a, 0, 0, 0);     \
    a = __builtin_amdgcn_mfma_f32_16x16x32_bf16(Ax[0], Bi[2], a, 0, 0, 0);     \
    a = __builtin_amdgcn_mfma_f32_16x16x32_bf16(Ax[1], Bi[0], a, 0, 0, 0);     \
    a = __builtin_amdgcn_mfma_f32_16x16x32_bf16(Ax[0], Bi[1], a, 0, 0, 0);     \
    a = __builtin_amdgcn_mfma_f32_16x16x32_bf16(Ax[0], Bi[0], a, 0, 0, 0);

#define MM1(qq)                                                                \
    {                                                                          \
        short8 Af[3];                                                          \
        const char* ap = bufc + (qq)*16*ROWB + abase;                          \
        _Pragma("unroll")                                                      \
        for (int p = 0; p < 3; ++p) Af[p] = *(const short8*)(ap + p*APL);      \
        f32x4 x0 = acc[qq][0], x1 = acc[qq][1];                                \
        MFMA6(Af, Bf[0], x0)                                                   \
        MFMA6(Af, Bf[1], x1)                                                   \
        acc[qq][0] = x0; acc[qq][1] = x1;                                      \
    }

// ---------------------------------------------------------------------------
// Encoder v13: one block per pair (512 thr, 8 waves x 2 nt), DOUBLE-BUFFERED
// Apl: build(kt+1)->buf^1 fused into the MFMA(kt) region (one barrier/kt),
// so split-VALU/LDS-writes interleave with MFMA chains within each wave.
// ---------------------------------------------------------------------------
__global__ __launch_bounds__(512, 4) void k_enc(
    const int*   __restrict__ lists,
    const int*   __restrict__ counts,
    const float* __restrict__ PQ,
    const unsigned short* __restrict__ W2f,
    const float* __restrict__ b2,    // (2,256)
    float* __restrict__ node_msg)
{
    const int lb   = (blockIdx.x & 7)*96 + (blockIdx.x >> 3);  // 768 = 8*96
    const int b    = lb / 24;
    const int pair = lb % 24;
    const int n0   = pair * 2;
    const int tid  = threadIdx.x;        // 0..511
    const int lane = tid & 63, wave = tid >> 6;
    const unsigned PSEL = 0x07060302u;

    __shared__ __align__(16) char Apl[2*ABUF];   // 53.76 KB (double buffer)
    __shared__ int rowinfo_s[TMAX*16];

    const int c00 = counts[(b*NN + n0    )*2 + 0];
    const int c10 = counts[(b*NN + n0    )*2 + 1];
    const int c01 = counts[(b*NN + n0 + 1)*2 + 0];
    const int c11 = counts[(b*NN + n0 + 1)*2 + 1];
    const int tA  = c00 + c01, tB = c10 + c11;
    const int tAt = (tA + 15) >> 4, tBt = (tB + 15) >> 4;
    const int tiles = tAt + tBt;
    const int rows  = tiles*16;

    if (tid < TMAX*16) {
        const int r = tid;
        int g = 4, src = 0;
        if (r < tAt*16) {
            if (r < c00)     { src = lists[(b*NN + n0    )*LSTR + r];        g = 0; }
            else if (r < tA) { src = lists[(b*NN + n0 + 1)*LSTR + (r - c00)]; g = 1; }
        } else if (r < rows) {
            const int s = r - tAt*16;
            if (s < c10)     { src = lists[(b*NN + n0    )*LSTR + c00 + s];        g = 2; }
            else if (s < tB) { src = lists[(b*NN + n0 + 1)*LSTR + c01 + (s - c10)]; g = 3; }
        }
        rowinfo_s[r] = src | (g << 8);
    }
    __syncthreads();

    // per-thread build metadata (row = tid>>2, quad = tid&3) — loop-invariant
    const int brow  = tid >> 2, bquad = tid & 3;
    int bpoff = 0, bqoff = 0;
    bool bact = false;
    if (brow < rows) {
        const int info = rowinfo_s[brow];
        const int src  = info & 255;
        const int nd   = (info >> 8) & 1;
        const int tq   = (brow >= tAt*16) ? 1 : 0;
        bpoff = src*PQS      + tq*512 +       bquad*8;
        bqoff = (n0+nd)*PQS  + tq*512 + 256 + bquad*8;
        bact = true;
    }

    f32x4 acc[TMAX][2];
    #pragma unroll
    for (int q = 0; q < TMAX; ++q) {
        acc[q][0] = (f32x4){0.f, 0.f, 0.f, 0.f};
        acc[q][1] = (f32x4){0.f, 0.f, 0.f, 0.f};
    }

    const float* PQb = PQ + (size_t)b*NN*PQS;
    const int ntb  = wave*2;
    const int abase = (lane & 15)*ROWB + (lane >> 4)*16;

    // build A for k-tile kt into buffer buf
    auto build = [&](int kt, char* buf) {
        if (bact) {
            const float* pr = PQb + bpoff + kt*32;
            const float* qr = PQb + bqoff + kt*32;
            const float4 Pa = *(const float4*)pr, Pb = *(const float4*)(pr+4);
            const float4 Qa = *(const float4*)qr, Qb = *(const float4*)(qr+4);
            const float u0 = fmaxf(Pa.x + Qa.x, 0.f);
            const float u1 = fmaxf(Pa.y + Qa.y, 0.f);
            const float u2 = fmaxf(Pa.z + Qa.z, 0.f);
            const float u3 = fmaxf(Pa.w + Qa.w, 0.f);
            const float u4 = fmaxf(Pb.x + Qb.x, 0.f);
            const float u5 = fmaxf(Pb.y + Qb.y, 0.f);
            const float u6 = fmaxf(Pb.z + Qb.z, 0.f);
            const float u7 = fmaxf(Pb.w + Qb.w, 0.f);
            const Split3 s0 = split2(u0, u1, PSEL);
            const Split3 s1 = split2(u2, u3, PSEL);
            const Split3 s2 = split2(u4, u5, PSEL);
            const Split3 s3 = split2(u6, u7, PSEL);
            char* w = buf + brow*ROWB + bquad*16;
            PackA A0, A1, A2;
            A0.u[0]=s0.d0; A0.u[1]=s1.d0; A0.u[2]=s2.d0; A0.u[3]=s3.d0;
            A1.u[0]=s0.d1; A1.u[1]=s1.d1; A1.u[2]=s2.d1; A1.u[3]=s3.d1;
            A2.u[0]=s0.d2; A2.u[1]=s1.d2; A2.u[2]=s2.d2; A2.u[3]=s3.d2;
            *(short8*)(w)         = A0.s;
            *(short8*)(w + APL)   = A1.s;
            *(short8*)(w + 2*APL) = A2.s;
        }
    };

    build(0, Apl);
    __syncthreads();

    #pragma unroll 1
    for (int kt = 0; kt < 8; ++kt) {
        const int cur = kt & 1;
        const char* bufc = Apl + cur*ABUF;
        // fused region: build(kt+1) + MFMA(kt) — compiler interleaves
        if (kt < 7) build(kt+1, Apl + (cur^1)*ABUF);
        #pragma unroll
        for (int sec = 0; sec < 2; ++sec) {
            const int qlo = sec ? tAt : 0;
            const int qhi = sec ? tiles : tAt;
            if (qlo >= qhi) continue;
            short8 Bf[2][3];
            #pragma unroll
            for (int i = 0; i < 2; ++i)
                #pragma unroll
                for (int p = 0; p < 3; ++p)
                    Bf[i][p] = *(const short8*)(W2f + ((size_t)(sec*3+p)*65536
                                 + (size_t)kt*8192 + (size_t)(ntb + i)*512 + (size_t)lane*8));
            #pragma unroll
            for (int q = 0; q < TMAX; ++q) {
                if (q >= qlo && q < qhi) { MM1(q) }
            }
        }
        __syncthreads();
    }

    // ---- readout: relu(acc+b2), per-row node mask, shfl-reduce, store ----
    float b2v[2][2];
    #pragma unroll
    for (int t = 0; t < 2; ++t)
        #pragma unroll
        for (int i = 0; i < 2; ++i)
            b2v[t][i] = b2[t*HH + (ntb + i)*16 + (lane & 15)];

    float p0[2], p1[2];
    p0[0] = p0[1] = p1[0] = p1[1] = 0.f;
    #pragma unroll
    for (int q = 0; q < TMAX; ++q) {
        if (q < tiles) {
            const bool secB = (q >= tAt);
            int gv[4];
            #pragma unroll
            for (int rr = 0; rr < 4; ++rr)
                gv[rr] = rowinfo_s[q*16 + (lane >> 4)*4 + rr] >> 8;
            #pragma unroll
            for (int i = 0; i < 2; ++i) {
                const float bias = secB ? b2v[1][i] : b2v[0][i];
                #pragma unroll
                for (int rr = 0; rr < 4; ++rr) {
                    const float v = fmaxf(acc[q][i][rr] + bias, 0.f);
                    const bool valid = gv[rr] < 4;
                    p0[i] += (valid && !(gv[rr] & 1)) ? v : 0.f;
                    p1[i] += (valid &&  (gv[rr] & 1)) ? v : 0.f;
                }
            }
        }
    }
    #pragma unroll
    for (int i = 0; i < 2; ++i) {
        float v0 = p0[i], v1 = p1[i];
        v0 += __shfl_xor(v0, 16); v0 += __shfl_xor(v0, 32);
        v1 += __shfl_xor(v1, 16); v1 += __shfl_xor(v1, 32);
        if ((lane >> 4) == 0) {
            node_msg[((size_t)(b*NN + n0  ))*HH + (ntb + i)*16 + lane] = v0;
            node_msg[((size_t)(b*NN + n0+1))*HH + (ntb + i)*16 + lane] = v1;
        }
    }
}

// ---------------------------------------------------------------------------
// Decoder: 6 rows/block (256 blocks), fused PQ production. Unchanged.
// ---------------------------------------------------------------------------
__global__ __launch_bounds__(256, 2) void k_dec(
    float* __restrict__ state,
    const float* __restrict__ nm,
    const float* __restrict__ W1, const float* __restrict__ b1,   // (272,256)
    const float* __restrict__ W2, const float* __restrict__ b2,   // (256,256)
    const float* __restrict__ W3, const float* __restrict__ b3,   // (256,16)
    const float* __restrict__ eW1T,  // (2,256,32)
    const float* __restrict__ eb1,   // (2,256)
    float* __restrict__ PQ,
    float* __restrict__ out, int step)
{
    const int lb   = (blockIdx.x & 7)*32 + (blockIdx.x >> 3);
    const int b    = lb / 8;
    const int row0 = (lb % 8) * 6;
    const int c    = threadIdx.x;

    __shared__ float in_s[6][272];
    __shared__ float d1s[6][HH];
    __shared__ float stn[6][DD];

    for (int i = c; i < 6*272; i += 256) {
        const int m = i / 272, k = i % 272;
        const int r = row0 + m;
        in_s[m][k] = (k < DD)
            ? state[((size_t)b*NN + r)*DD + k]
            : nm[((size_t)b*NN + r)*HH + (k - DD)];
    }
    __syncthreads();

    float a0[6];
    {
        const float bb = b1[c];
        #pragma unroll
        for (int m = 0; m < 6; ++m) a0[m] = bb;
        #pragma unroll 2
        for (int k4 = 0; k4 < 68; ++k4) {
            const float* wr = W1 + (k4*4)*HH;
            const float w0=wr[c], w1_=wr[HH+c], w2_=wr[2*HH+c], w3=wr[3*HH+c];
            #pragma unroll
            for (int m = 0; m < 6; ++m) {
                const float4 h = *(const float4*)&in_s[m][k4*4];
                a0[m] = fmaf(h.x,w0, fmaf(h.y,w1_, fmaf(h.z,w2_, fmaf(h.w,w3, a0[m]))));
            }
        }
        #pragma unroll
        for (int m = 0; m < 6; ++m) d1s[m][c] = fmaxf(a0[m], 0.f);
    }
    __syncthreads();
    {
        const float bb = b2[c];
        #pragma unroll
        for (int m = 0; m < 6; ++m) a0[m] = bb;
        #pragma unroll 2
        for (int k4 = 0; k4 < 64; ++k4) {
            const float* wr = W2 + (k4*4)*HH;
            const float w0=wr[c], w1_=wr[HH+c], w2_=wr[2*HH+c], w3=wr[3*HH+c];
            #pragma unroll
            for (int m = 0; m < 6; ++m) {
                const float4 h = *(const float4*)&d1s[m][k4*4];
                a0[m] = fmaf(h.x,w0, fmaf(h.y,w1_, fmaf(h.z,w2_, fmaf(h.w,w3, a0[m]))));
            }
        }
        __syncthreads();
        #pragma unroll
        for (int m = 0; m < 6; ++m) in_s[m][c] = fmaxf(a0[m], 0.f);
    }
    __syncthreads();
    if (c < 96) {
        const int m = c >> 4, cc = c & 15;
        float a = b3[cc];
        #pragma unroll 4
        for (int k4 = 0; k4 < 64; ++k4) {
            const float4 h = *(const float4*)&in_s[m][k4*4];
            a += h.x*W3[(k4*4+0)*16+cc] + h.y*W3[(k4*4+1)*16+cc]
               + h.z*W3[(k4*4+2)*16+cc] + h.w*W3[(k4*4+3)*16+cc];
        }
        const int r = row0 + m;
        const float v = state[((size_t)b*NN + r)*DD + cc] + a;
        state[((size_t)b*NN + r)*DD + cc] = v;
        out[(((size_t)b*NPRED + step)*NN + r)*DD + cc] = v;
        stn[m][cc] = v;
    }
    __syncthreads();
    float4 sm[6][4];
    #pragma unroll
    for (int m = 0; m < 6; ++m)
        #pragma unroll
        for (int f4 = 0; f4 < 4; ++f4)
            sm[m][f4] = *(const float4*)&stn[m][f4*4];
    #pragma unroll
    for (int k = 0; k < 4; ++k) {
        const int combo = c + 256*k;
        const int cc = combo & 255;
        const int pq = (combo >> 8) & 1;
        const int t  = combo >> 9;
        const float* wc = eW1T + ((size_t)t*HH + cc)*32 + pq*16;
        float4 w[4];
        #pragma unroll
        for (int f4 = 0; f4 < 4; ++f4) w[f4] = ((const float4*)wc)[f4];
        const float bias = pq ? eb1[t*HH + cc] : 0.f;
        #pragma unroll
        for (int m = 0; m < 6; ++m) {
            float v = bias;
            #pragma unroll
            for (int f4 = 0; f4 < 4; ++f4) {
                const float4 s = sm[m][f4];
                v = fmaf(s.x,w[f4].x, fmaf(s.y,w[f4].y, fmaf(s.z,w[f4].z, fmaf(s.w,w[f4].w, v))));
            }
            PQ[(size_t)(b*NN + row0 + m)*PQS + t*512 + pq*256 + cc] = v;
        }
    }
}

// ---------------------------------------------------------------------------
extern "C" void kernel_launch(void* const* d_in, const int* in_sizes, int n_in,
                              void* d_out, int out_size, void* d_ws, size_t ws_size,
                              hipStream_t stream)
{
    const float* time_segs  = (const float*)d_in[0];
    const float* edge_types = (const float*)d_in[1];
    const float* enc_W1 = (const float*)d_in[4];
    const float* enc_b1 = (const float*)d_in[5];
    const float* enc_W2 = (const float*)d_in[6];
    const float* enc_b2 = (const float*)d_in[7];
    const float* dec_W1 = (const float*)d_in[8];
    const float* dec_b1 = (const float*)d_in[9];
    const float* dec_W2 = (const float*)d_in[10];
    const float* dec_b2 = (const float*)d_in[11];
    const float* out_W  = (const float*)d_in[12];
    const float* out_b  = (const float*)d_in[13];
    float* out = (float*)d_out;

    // workspace (~9.3 MB)
    float* state    = (float*)d_ws;                    // 24576 f
    float* node_msg = state + BB*NN*DD;                // 393216 f
    float* W1T      = node_msg + BB*NN*HH;             // 16384 f
    unsigned short* W2f = (unsigned short*)(W1T + 2*HH*32);   // 393216 us
    int*   lists    = (int*)(W2f + 2*3*65536);         // 86016 i
    int*   counts   = lists + BB*NN*LSTR;              // 3072 i
    float* PQ       = (float*)(counts + BB*NN*2);      // 1597440 f

    k_setup<<<384, 256, 0, stream>>>(time_segs, edge_types, enc_W1, enc_W2,
                                     enc_b1, state, W1T, W2f, PQ, lists, counts);
    for (int stp = 0; stp < NPRED; ++stp) {
        k_enc<<<BB*24, 512, 0, stream>>>(lists, counts, PQ, W2f,
                                         enc_b2, node_msg);
        k_dec<<<BB*8, 256, 0, stream>>>(state, node_msg,
                                        dec_W1, dec_b1, dec_W2, dec_b2,
                                        out_W, out_b, W1T, enc_b1, PQ, out, stp);
    }
}

// Round 24
// 559.063 us; speedup vs baseline: 1.3111x; 1.0221x over previous
//
#include <hip/hip_runtime.h>

#define NN    48
#define DD    16
#define HH    256
#define EE    2256
#define BB    32
#define NPRED 8
#define LSTR  56
#define PQS   1040                   // PQ per-node stride (floats), de-pow2
#define TMAX  7                      // packed tiles/pair <= 7 (tA+tB<=94)
#define ROWB  80                     // A-plane row stride bytes (5x16B, 2-way banks)
#define APL   (TMAX*16*ROWB)         // 8960 B per plane
#define ABUF  (3*APL)                // one dbuf half (3 planes) = 26880 B

typedef __attribute__((ext_vector_type(4))) float f32x4;
typedef __attribute__((ext_vector_type(8))) short short8;

__device__ __forceinline__ float bf2f(unsigned short h) {
    union { unsigned u; float f; } v; v.u = ((unsigned)h) << 16; return v.f;
}
__device__ __forceinline__ unsigned short f2bf(float x) {
    union { float f; unsigned u; } v; v.f = x;
    unsigned r = v.u + 0x7fffu + ((v.u >> 16) & 1u);
    return (unsigned short)(r >> 16);
}
__device__ __forceinline__ unsigned perm_hi16(unsigned xB, unsigned xA, unsigned sel) {
    unsigned d;
    asm("v_perm_b32 %0, %1, %2, %3" : "=v"(d) : "v"(xB), "v"(xA), "s"(sel));
    return d;
}
struct Split3 { unsigned d0, d1, d2; };
__device__ __forceinline__ Split3 split2(float u0, float u1, unsigned sel)
{
    union F { float f; unsigned u; };
    Split3 o;
    F x0, x1; x0.f = u0; x1.f = u1;
    o.d0 = perm_hi16(x1.u, x0.u, sel);
    F h0a, h0b; h0a.u = x0.u & 0xffff0000u; h0b.u = x1.u & 0xffff0000u;
    F e0a, e0b; e0a.f = u0 - h0a.f; e0b.f = u1 - h0b.f;
    o.d1 = perm_hi16(e0b.u, e0a.u, sel);
    F h1a, h1b; h1a.u = e0a.u & 0xffff0000u; h1b.u = e0b.u & 0xffff0000u;
    F e1a, e1b; e1a.f = e0a.f - h1a.f; e1b.f = e0b.f - h1b.f;
    o.d2 = perm_hi16(e1b.u, e1a.u, sel);
    return o;
}
union PackA { unsigned u[4]; short8 s; };

// ---------------------------------------------------------------------------
// Setup (768 blocks — latency-bound, finer spread).
// ---------------------------------------------------------------------------
__global__ __launch_bounds__(256) void k_setup(
    const float* __restrict__ time_segs,
    const float* __restrict__ edge_types,
    const float* __restrict__ W1,      // (2,32,256)
    const float* __restrict__ W2,      // (2,256,256)
    const float* __restrict__ b1,      // (2,256)
    float* __restrict__ state,
    float* __restrict__ W1T,           // (2,256,32)
    unsigned short* __restrict__ W2f,  // 393216
    float* __restrict__ PQ,
    int* __restrict__ lists,
    int* __restrict__ counts)
{
    const int tid = blockIdx.x * 256 + threadIdx.x;
    const int NT = 768*256;
    for (int i = tid; i < BB*NN*DD; i += NT)
        state[i] = time_segs[i];
    for (int i = tid; i < 2*HH*32; i += NT) {
        const int t = i >> 13, r = i & 8191, h = r >> 5, f = r & 31;
        W1T[i] = W1[(t*32 + f)*HH + h];
    }
    for (int i = tid; i < 2*8*16*64*8; i += NT) {
        const int j  = i & 7, l = (i >> 3) & 63, nt = (i >> 9) & 15;
        const int kt = (i >> 13) & 7, t = (i >> 16) & 1;
        const int k = kt*32 + ((l >> 4) << 3) + j;
        const int n = nt*16 + (l & 15);
        const float w = W2[((size_t)t*HH + k)*HH + n];
        const unsigned short h0 = f2bf(w);  const float r1 = w  - bf2f(h0);
        const unsigned short h1 = f2bf(r1); const float r2 = r1 - bf2f(h1);
        const unsigned short h2 = f2bf(r2);
        const size_t rest = (size_t)kt*8192 + nt*512 + l*8 + j;
        W2f[(size_t)(t*3+0)*65536 + rest] = h0;
        W2f[(size_t)(t*3+1)*65536 + rest] = h1;
        W2f[(size_t)(t*3+2)*65536 + rest] = h2;
    }
    for (int i = tid; i < BB*NN*1024; i += NT) {
        const int c  = i & 255;
        const int pq = (i >> 8) & 1;
        const int t  = (i >> 9) & 1;
        const int nb = i >> 10;
        float v = pq ? b1[t*HH + c] : 0.f;
        #pragma unroll
        for (int f = 0; f < DD; ++f)
            v = fmaf(time_segs[nb*DD + f], W1[(t*32 + pq*16 + f)*HH + c], v);
        PQ[(size_t)nb*PQS + (i & 1023)] = v;
    }
    if (tid < BB*NN) {
        const int b = tid / NN;
        const int n = tid % NN;
        int* lst = lists + tid * LSTR;
        int c = 0;
        for (int s = 0; s < NN; ++s) {
            if (s == n) continue;
            const int e = s * 47 + (n > s ? n - 1 : n);
            if (edge_types[((size_t)b*EE + e)*3 + 1] > 0.5f) lst[c++] = s;
        }
        const int c1 = c;
        for (int s = 0; s < NN; ++s) {
            if (s == n) continue;
            const int e = s * 47 + (n > s ? n - 1 : n);
            if (edge_types[((size_t)b*EE + e)*3 + 2] > 0.5f) lst[c++] = s;
        }
        counts[tid*2 + 0] = c1;
        counts[tid*2 + 1] = c - c1;
        for (int i = c; i < LSTR; ++i) lst[i] = 0;
    }
}

#define MFMA6(Ax, Bi, a)                                                       \
    a = __builtin_amdgcn_mfma_f32_16x16x32_bf16(Ax[2], Bi[0], a, 0, 0, 0);     \
    a = __builtin_amdgcn_mfma_f32_16x16x32_bf16(Ax[1], Bi[1], a, 0, 0, 0);     \
    a = __builtin_amdgcn_mfma_f32_16x16x32_bf16(Ax[0], Bi[2], a, 0, 0, 0);     \
    a = __builtin_amdgcn_mfma_f32_16x16x32_bf16(Ax[1], Bi[0], a, 0, 0, 0);     \
    a = __builtin_amdgcn_mfma_f32_16x16x32_bf16(Ax[0], Bi[1], a, 0, 0, 0);     \
    a = __builtin_amdgcn_mfma_f32_16x16x32_bf16(Ax[0], Bi[0], a, 0, 0, 0);

#define MM1(qq)                                                                \
    {                                                                          \
        short8 Af[3];                                                          \
        const char* ap = bufc + (qq)*16*ROWB + abase;                          \
        _Pragma("unroll")                                                      \
        for (int p = 0; p < 3; ++p) Af[p] = *(const short8*)(ap + p*APL);      \
        f32x4 x0 = acc[qq][0], x1 = acc[qq][1];                                \
        __builtin_amdgcn_s_setprio(1);                                         \
        MFMA6(Af, Bf[0], x0)                                                   \
        MFMA6(Af, Bf[1], x1)                                                   \
        __builtin_amdgcn_s_setprio(0);                                         \
        acc[qq][0] = x0; acc[qq][1] = x1;                                      \
    }

// ---------------------------------------------------------------------------
// Encoder v13b: R23 structure + T5 s_setprio around MFMA clusters (the 2
// independent blocks/CU are at different phases -> scheduler favors the
// MFMA-issuing waves).
// ---------------------------------------------------------------------------
__global__ __launch_bounds__(512, 4) void k_enc(
    const int*   __restrict__ lists,
    const int*   __restrict__ counts,
    const float* __restrict__ PQ,
    const unsigned short* __restrict__ W2f,
    const float* __restrict__ b2,    // (2,256)
    float* __restrict__ node_msg)
{
    const int lb   = (blockIdx.x & 7)*96 + (blockIdx.x >> 3);  // 768 = 8*96
    const int b    = lb / 24;
    const int pair = lb % 24;
    const int n0   = pair * 2;
    const int tid  = threadIdx.x;        // 0..511
    const int lane = tid & 63, wave = tid >> 6;
    const unsigned PSEL = 0x07060302u;

    __shared__ __align__(16) char Apl[2*ABUF];   // 53.76 KB (double buffer)
    __shared__ int rowinfo_s[TMAX*16];

    const int c00 = counts[(b*NN + n0    )*2 + 0];
    const int c10 = counts[(b*NN + n0    )*2 + 1];
    const int c01 = counts[(b*NN + n0 + 1)*2 + 0];
    const int c11 = counts[(b*NN + n0 + 1)*2 + 1];
    const int tA  = c00 + c01, tB = c10 + c11;
    const int tAt = (tA + 15) >> 4, tBt = (tB + 15) >> 4;
    const int tiles = tAt + tBt;
    const int rows  = tiles*16;

    if (tid < TMAX*16) {
        const int r = tid;
        int g = 4, src = 0;
        if (r < tAt*16) {
            if (r < c00)     { src = lists[(b*NN + n0    )*LSTR + r];        g = 0; }
            else if (r < tA) { src = lists[(b*NN + n0 + 1)*LSTR + (r - c00)]; g = 1; }
        } else if (r < rows) {
            const int s = r - tAt*16;
            if (s < c10)     { src = lists[(b*NN + n0    )*LSTR + c00 + s];        g = 2; }
            else if (s < tB) { src = lists[(b*NN + n0 + 1)*LSTR + c01 + (s - c10)]; g = 3; }
        }
        rowinfo_s[r] = src | (g << 8);
    }
    __syncthreads();

    // per-thread build metadata (row = tid>>2, quad = tid&3) — loop-invariant
    const int brow  = tid >> 2, bquad = tid & 3;
    int bpoff = 0, bqoff = 0;
    bool bact = false;
    if (brow < rows) {
        const int info = rowinfo_s[brow];
        const int src  = info & 255;
        const int nd   = (info >> 8) & 1;
        const int tq   = (brow >= tAt*16) ? 1 : 0;
        bpoff = src*PQS      + tq*512 +       bquad*8;
        bqoff = (n0+nd)*PQS  + tq*512 + 256 + bquad*8;
        bact = true;
    }

    f32x4 acc[TMAX][2];
    #pragma unroll
    for (int q = 0; q < TMAX; ++q) {
        acc[q][0] = (f32x4){0.f, 0.f, 0.f, 0.f};
        acc[q][1] = (f32x4){0.f, 0.f, 0.f, 0.f};
    }

    const float* PQb = PQ + (size_t)b*NN*PQS;
    const int ntb  = wave*2;
    const int abase = (lane & 15)*ROWB + (lane >> 4)*16;

    auto build = [&](int kt, char* buf) {
        if (bact) {
            const float* pr = PQb + bpoff + kt*32;
            const float* qr = PQb + bqoff + kt*32;
            const float4 Pa = *(const float4*)pr, Pb = *(const float4*)(pr+4);
            const float4 Qa = *(const float4*)qr, Qb = *(const float4*)(qr+4);
            const float u0 = fmaxf(Pa.x + Qa.x, 0.f);
            const float u1 = fmaxf(Pa.y + Qa.y, 0.f);
            const float u2 = fmaxf(Pa.z + Qa.z, 0.f);
            const float u3 = fmaxf(Pa.w + Qa.w, 0.f);
            const float u4 = fmaxf(Pb.x + Qb.x, 0.f);
            const float u5 = fmaxf(Pb.y + Qb.y, 0.f);
            const float u6 = fmaxf(Pb.z + Qb.z, 0.f);
            const float u7 = fmaxf(Pb.w + Qb.w, 0.f);
            const Split3 s0 = split2(u0, u1, PSEL);
            const Split3 s1 = split2(u2, u3, PSEL);
            const Split3 s2 = split2(u4, u5, PSEL);
            const Split3 s3 = split2(u6, u7, PSEL);
            char* w = buf + brow*ROWB + bquad*16;
            PackA A0, A1, A2;
            A0.u[0]=s0.d0; A0.u[1]=s1.d0; A0.u[2]=s2.d0; A0.u[3]=s3.d0;
            A1.u[0]=s0.d1; A1.u[1]=s1.d1; A1.u[2]=s2.d1; A1.u[3]=s3.d1;
            A2.u[0]=s0.d2; A2.u[1]=s1.d2; A2.u[2]=s2.d2; A2.u[3]=s3.d2;
            *(short8*)(w)         = A0.s;
            *(short8*)(w + APL)   = A1.s;
            *(short8*)(w + 2*APL) = A2.s;
        }
    };

    build(0, Apl);
    __syncthreads();

    #pragma unroll 1
    for (int kt = 0; kt < 8; ++kt) {
        const int cur = kt & 1;
        const char* bufc = Apl + cur*ABUF;
        if (kt < 7) build(kt+1, Apl + (cur^1)*ABUF);
        #pragma unroll
        for (int sec = 0; sec < 2; ++sec) {
            const int qlo = sec ? tAt : 0;
            const int qhi = sec ? tiles : tAt;
            if (qlo >= qhi) continue;
            short8 Bf[2][3];
            #pragma unroll
            for (int i = 0; i < 2; ++i)
                #pragma unroll
                for (int p = 0; p < 3; ++p)
                    Bf[i][p] = *(const short8*)(W2f + ((size_t)(sec*3+p)*65536
                                 + (size_t)kt*8192 + (size_t)(ntb + i)*512 + (size_t)lane*8));
            #pragma unroll
            for (int q = 0; q < TMAX; ++q) {
                if (q >= qlo && q < qhi) { MM1(q) }
            }
        }
        __syncthreads();
    }

    // ---- readout: relu(acc+b2), per-row node mask, shfl-reduce, store ----
    float b2v[2][2];
    #pragma unroll
    for (int t = 0; t < 2; ++t)
        #pragma unroll
        for (int i = 0; i < 2; ++i)
            b2v[t][i] = b2[t*HH + (ntb + i)*16 + (lane & 15)];

    float p0[2], p1[2];
    p0[0] = p0[1] = p1[0] = p1[1] = 0.f;
    #pragma unroll
    for (int q = 0; q < TMAX; ++q) {
        if (q < tiles) {
            const bool secB = (q >= tAt);
            int gv[4];
            #pragma unroll
            for (int rr = 0; rr < 4; ++rr)
                gv[rr] = rowinfo_s[q*16 + (lane >> 4)*4 + rr] >> 8;
            #pragma unroll
            for (int i = 0; i < 2; ++i) {
                const float bias = secB ? b2v[1][i] : b2v[0][i];
                #pragma unroll
                for (int rr = 0; rr < 4; ++rr) {
                    const float v = fmaxf(acc[q][i][rr] + bias, 0.f);
                    const bool valid = gv[rr] < 4;
                    p0[i] += (valid && !(gv[rr] & 1)) ? v : 0.f;
                    p1[i] += (valid &&  (gv[rr] & 1)) ? v : 0.f;
                }
            }
        }
    }
    #pragma unroll
    for (int i = 0; i < 2; ++i) {
        float v0 = p0[i], v1 = p1[i];
        v0 += __shfl_xor(v0, 16); v0 += __shfl_xor(v0, 32);
        v1 += __shfl_xor(v1, 16); v1 += __shfl_xor(v1, 32);
        if ((lane >> 4) == 0) {
            node_msg[((size_t)(b*NN + n0  ))*HH + (ntb + i)*16 + lane] = v0;
            node_msg[((size_t)(b*NN + n0+1))*HH + (ntb + i)*16 + lane] = v1;
        }
    }
}

// ---------------------------------------------------------------------------
// Decoder: 6 rows/block (256 blocks), fused PQ production. Unchanged.
// ---------------------------------------------------------------------------
__global__ __launch_bounds__(256, 2) void k_dec(
    float* __restrict__ state,
    const float* __restrict__ nm,
    const float* __restrict__ W1, const float* __restrict__ b1,   // (272,256)
    const float* __restrict__ W2, const float* __restrict__ b2,   // (256,256)
    const float* __restrict__ W3, const float* __restrict__ b3,   // (256,16)
    const float* __restrict__ eW1T,  // (2,256,32)
    const float* __restrict__ eb1,   // (2,256)
    float* __restrict__ PQ,
    float* __restrict__ out, int step)
{
    const int lb   = (blockIdx.x & 7)*32 + (blockIdx.x >> 3);
    const int b    = lb / 8;
    const int row0 = (lb % 8) * 6;
    const int c    = threadIdx.x;

    __shared__ float in_s[6][272];
    __shared__ float d1s[6][HH];
    __shared__ float stn[6][DD];

    for (int i = c; i < 6*272; i += 256) {
        const int m = i / 272, k = i % 272;
        const int r = row0 + m;
        in_s[m][k] = (k < DD)
            ? state[((size_t)b*NN + r)*DD + k]
            : nm[((size_t)b*NN + r)*HH + (k - DD)];
    }
    __syncthreads();

    float a0[6];
    {
        const float bb = b1[c];
        #pragma unroll
        for (int m = 0; m < 6; ++m) a0[m] = bb;
        #pragma unroll 2
        for (int k4 = 0; k4 < 68; ++k4) {
            const float* wr = W1 + (k4*4)*HH;
            const float w0=wr[c], w1_=wr[HH+c], w2_=wr[2*HH+c], w3=wr[3*HH+c];
            #pragma unroll
            for (int m = 0; m < 6; ++m) {
                const float4 h = *(const float4*)&in_s[m][k4*4];
                a0[m] = fmaf(h.x,w0, fmaf(h.y,w1_, fmaf(h.z,w2_, fmaf(h.w,w3, a0[m]))));
            }
        }
        #pragma unroll
        for (int m = 0; m < 6; ++m) d1s[m][c] = fmaxf(a0[m], 0.f);
    }
    __syncthreads();
    {
        const float bb = b2[c];
        #pragma unroll
        for (int m = 0; m < 6; ++m) a0[m] = bb;
        #pragma unroll 2
        for (int k4 = 0; k4 < 64; ++k4) {
            const float* wr = W2 + (k4*4)*HH;
            const float w0=wr[c], w1_=wr[HH+c], w2_=wr[2*HH+c], w3=wr[3*HH+c];
            #pragma unroll
            for (int m = 0; m < 6; ++m) {
                const float4 h = *(const float4*)&d1s[m][k4*4];
                a0[m] = fmaf(h.x,w0, fmaf(h.y,w1_, fmaf(h.z,w2_, fmaf(h.w,w3, a0[m]))));
            }
        }
        __syncthreads();
        #pragma unroll
        for (int m = 0; m < 6; ++m) in_s[m][c] = fmaxf(a0[m], 0.f);
    }
    __syncthreads();
    if (c < 96) {
        const int m = c >> 4, cc = c & 15;
        float a = b3[cc];
        #pragma unroll 4
        for (int k4 = 0; k4 < 64; ++k4) {
            const float4 h = *(const float4*)&in_s[m][k4*4];
            a += h.x*W3[(k4*4+0)*16+cc] + h.y*W3[(k4*4+1)*16+cc]
               + h.z*W3[(k4*4+2)*16+cc] + h.w*W3[(k4*4+3)*16+cc];
        }
        const int r = row0 + m;
        const float v = state[((size_t)b*NN + r)*DD + cc] + a;
        state[((size_t)b*NN + r)*DD + cc] = v;
        out[(((size_t)b*NPRED + step)*NN + r)*DD + cc] = v;
        stn[m][cc] = v;
    }
    __syncthreads();
    float4 sm[6][4];
    #pragma unroll
    for (int m = 0; m < 6; ++m)
        #pragma unroll
        for (int f4 = 0; f4 < 4; ++f4)
            sm[m][f4] = *(const float4*)&stn[m][f4*4];
    #pragma unroll
    for (int k = 0; k < 4; ++k) {
        const int combo = c + 256*k;
        const int cc = combo & 255;
        const int pq = (combo >> 8) & 1;
        const int t  = combo >> 9;
        const float* wc = eW1T + ((size_t)t*HH + cc)*32 + pq*16;
        float4 w[4];
        #pragma unroll
        for (int f4 = 0; f4 < 4; ++f4) w[f4] = ((const float4*)wc)[f4];
        const float bias = pq ? eb1[t*HH + cc] : 0.f;
        #pragma unroll
        for (int m = 0; m < 6; ++m) {
            float v = bias;
            #pragma unroll
            for (int f4 = 0; f4 < 4; ++f4) {
                const float4 s = sm[m][f4];
                v = fmaf(s.x,w[f4].x, fmaf(s.y,w[f4].y, fmaf(s.z,w[f4].z, fmaf(s.w,w[f4].w, v))));
            }
            PQ[(size_t)(b*NN + row0 + m)*PQS + t*512 + pq*256 + cc] = v;
        }
    }
}

// ---------------------------------------------------------------------------
extern "C" void kernel_launch(void* const* d_in, const int* in_sizes, int n_in,
                              void* d_out, int out_size, void* d_ws, size_t ws_size,
                              hipStream_t stream)
{
    const float* time_segs  = (const float*)d_in[0];
    const float* edge_types = (const float*)d_in[1];
    const float* enc_W1 = (const float*)d_in[4];
    const float* enc_b1 = (const float*)d_in[5];
    const float* enc_W2 = (const float*)d_in[6];
    const float* enc_b2 = (const float*)d_in[7];
    const float* dec_W1 = (const float*)d_in[8];
    const float* dec_b1 = (const float*)d_in[9];
    const float* dec_W2 = (const float*)d_in[10];
    const float* dec_b2 = (const float*)d_in[11];
    const float* out_W  = (const float*)d_in[12];
    const float* out_b  = (const float*)d_in[13];
    float* out = (float*)d_out;

    // workspace (~9.3 MB)
    float* state    = (float*)d_ws;                    // 24576 f
    float* node_msg = state + BB*NN*DD;                // 393216 f
    float* W1T      = node_msg + BB*NN*HH;             // 16384 f
    unsigned short* W2f = (unsigned short*)(W1T + 2*HH*32);   // 393216 us
    int*   lists    = (int*)(W2f + 2*3*65536);         // 86016 i
    int*   counts   = lists + BB*NN*LSTR;              // 3072 i
    float* PQ       = (float*)(counts + BB*NN*2);      // 1597440 f

    k_setup<<<768, 256, 0, stream>>>(time_segs, edge_types, enc_W1, enc_W2,
                                     enc_b1, state, W1T, W2f, PQ, lists, counts);
    for (int stp = 0; stp < NPRED; ++stp) {
        k_enc<<<BB*24, 512, 0, stream>>>(lists, counts, PQ, W2f,
                                         enc_b2, node_msg);
        k_dec<<<BB*8, 256, 0, stream>>>(state, node_msg,
                                        dec_W1, dec_b1, dec_W2, dec_b2,
                                        out_W, out_b, W1T, enc_b1, PQ, out, stp);
    }
}